// Round 1
// baseline (4070.282 us; speedup 1.0000x reference)
//
#include <hip/hip_runtime.h>
#include <math.h>

// ---------------------------------------------------------------------------
// Transformer-XL RelPartialLearnableDecoderLayer, fp32 baseline.
// qlen=512 mlen=512 klen=1024 bsz=4 d_model=1024 d_inner=4096 nh=16 dh=64
// rel_shift closed form: BD_shifted[i,j] = BD_raw[i, j+511-i]; mask j > i+512.
// ---------------------------------------------------------------------------

#define QLEN 512
#define MLEN 512
#define KLEN 1024
#define BSZ  4
#define DM   1024
#define DI   4096
#define NH   16
#define DH   64
#define HC   (3*DM)       // heads cols = 3072
#define HR   (KLEN*BSZ)   // 4096 rows of cat
#define NROWS (QLEN*BSZ)  // 2048

enum { ACT_NONE = 0, ACT_RELU = 1, ACT_SIG = 2, ACT_TANH = 3 };

// ---------------- wave/block reductions ----------------
__device__ __forceinline__ float waveSum(float v) {
#pragma unroll
  for (int o = 32; o; o >>= 1) v += __shfl_down(v, o, 64);
  return v;
}
__device__ __forceinline__ float waveMax(float v) {
#pragma unroll
  for (int o = 32; o; o >>= 1) v = fmaxf(v, __shfl_down(v, o, 64));
  return v;
}

// ---------------- LayerNorm (one block per 1024-wide row) ----------------
// CONCAT: rows [0,2048) from a (mems), rows [2048,4096) from a2 (w).
template <bool CONCAT>
__global__ __launch_bounds__(256) void ln_kernel(
    const float* __restrict__ a, const float* __restrict__ a2,
    const float* __restrict__ wt, const float* __restrict__ bs,
    float* __restrict__ dst) {
  const int row = blockIdx.x;
  const int tid = threadIdx.x;
  const float* srow;
  if (CONCAT)
    srow = (row < MLEN * BSZ) ? a + (size_t)row * DM
                              : a2 + (size_t)(row - MLEN * BSZ) * DM;
  else
    srow = a + (size_t)row * DM;
  float4 x = *(const float4*)(srow + tid * 4);
  float s = x.x + x.y + x.z + x.w;
  float q = x.x * x.x + x.y * x.y + x.z * x.z + x.w * x.w;
  __shared__ float2 red[4];
  float2 p;
  p.x = waveSum(s);
  p.y = waveSum(q);
  if ((tid & 63) == 0) red[tid >> 6] = p;
  __syncthreads();
  float S = red[0].x + red[1].x + red[2].x + red[3].x;
  float Q = red[0].y + red[1].y + red[2].y + red[3].y;
  const float inv = 1.0f / DM;
  float mu = S * inv;
  float var = Q * inv - mu * mu;
  float rs = rsqrtf(var + 1e-5f);
  float4 w4 = *(const float4*)(wt + tid * 4);
  float4 b4 = *(const float4*)(bs + tid * 4);
  float4 o;
  o.x = (x.x - mu) * rs * w4.x + b4.x;
  o.y = (x.y - mu) * rs * w4.y + b4.y;
  o.z = (x.z - mu) * rs * w4.z + b4.z;
  o.w = (x.w - mu) * rs * w4.w + b4.w;
  *(float4*)(dst + (size_t)row * DM + tid * 4) = o;
}

// ---------------- generic fp32 GEMM: C = act(A@B [+C] [+bias]) -------------
// BM in {64,128}, BN=128, BK=8, 256 threads, per-thread (BM/16)x8 microtile.
// All M multiples of BM, N multiples of 128, K multiples of 8 (true here).
template <int BM, int ACT, bool BETA, bool BIAS>
__global__ __launch_bounds__(256) void gemm_k(
    const float* __restrict__ A, const float* __restrict__ B,
    float* __restrict__ C, const float* __restrict__ bias,
    int M, int N, int K) {
  constexpr int BN = 128, BK = 8, TM = BM / 16;
  __shared__ float As[BK][BM];
  __shared__ float Bs[BK][BN];
  const int tid = threadIdx.x;
  const int row0 = blockIdx.y * BM;
  const int col0 = blockIdx.x * BN;
  const int tr = (tid >> 4) * TM;
  const int tc = (tid & 15) * 8;
  const int bkr = tid >> 5, bcc = (tid & 31) * 4;
  float acc[TM][8];
#pragma unroll
  for (int i = 0; i < TM; i++)
#pragma unroll
    for (int j = 0; j < 8; j++) acc[i][j] = 0.f;

  for (int k0 = 0; k0 < K; k0 += BK) {
    if constexpr (BM == 128) {
      const int ar = tid >> 1, ak = (tid & 1) * 4;
      float4 a4 = *(const float4*)(A + (size_t)(row0 + ar) * K + k0 + ak);
      As[ak + 0][ar] = a4.x;
      As[ak + 1][ar] = a4.y;
      As[ak + 2][ar] = a4.z;
      As[ak + 3][ar] = a4.w;
    } else {
      const int ar = tid >> 2, ak = (tid & 3) * 2;
      float2 a2 = *(const float2*)(A + (size_t)(row0 + ar) * K + k0 + ak);
      As[ak + 0][ar] = a2.x;
      As[ak + 1][ar] = a2.y;
    }
    *(float4*)&Bs[bkr][bcc] =
        *(const float4*)(B + (size_t)(k0 + bkr) * N + col0 + bcc);
    __syncthreads();
#pragma unroll
    for (int kk = 0; kk < BK; kk++) {
      float ra[TM], rb[8];
#pragma unroll
      for (int i = 0; i < TM; i += 4)
        *(float4*)&ra[i] = *(const float4*)&As[kk][tr + i];
      *(float4*)&rb[0] = *(const float4*)&Bs[kk][tc];
      *(float4*)&rb[4] = *(const float4*)&Bs[kk][tc + 4];
#pragma unroll
      for (int i = 0; i < TM; i++)
#pragma unroll
        for (int j = 0; j < 8; j++) acc[i][j] = fmaf(ra[i], rb[j], acc[i][j]);
    }
    __syncthreads();
  }
#pragma unroll
  for (int i = 0; i < TM; i++) {
    float* crow = C + (size_t)(row0 + tr + i) * N + col0 + tc;
#pragma unroll
    for (int j4 = 0; j4 < 8; j4 += 4) {
      float v[4];
#pragma unroll
      for (int t = 0; t < 4; t++) v[t] = acc[i][j4 + t];
      if constexpr (BETA) {
        float4 c4 = *(const float4*)(crow + j4);
        v[0] += c4.x; v[1] += c4.y; v[2] += c4.z; v[3] += c4.w;
      }
      if constexpr (BIAS) {
        float4 b4 = *(const float4*)(bias + col0 + tc + j4);
        v[0] += b4.x; v[1] += b4.y; v[2] += b4.z; v[3] += b4.w;
      }
#pragma unroll
      for (int t = 0; t < 4; t++) {
        if constexpr (ACT == ACT_RELU) v[t] = fmaxf(v[t], 0.f);
        else if constexpr (ACT == ACT_SIG) v[t] = 1.f / (1.f + expf(-v[t]));
        else if constexpr (ACT == ACT_TANH) v[t] = tanhf(v[t]);
      }
      float4 o; o.x = v[0]; o.y = v[1]; o.z = v[2]; o.w = v[3];
      *(float4*)(crow + j4) = o;
    }
  }
}

// ---------------- QK^T batched per head, K=64 ----------------
// PASS=1: BD raw = (q+r_r_bias) @ rk^T          -> out[n][i][j]  (no scale)
// PASS=2: score = ((q+r_w_bias)@k^T + shift(BD)) * 0.125, masked -> -inf
// grid: (j-tile 16, i-tile 8, head 16); per-b launch.
template <int PASS>
__global__ __launch_bounds__(256) void qk_kernel(
    const float* __restrict__ heads, const float* __restrict__ rkm,
    const float* __restrict__ qbias, float* __restrict__ outp,
    const float* __restrict__ s2, int b) {
  const int j0 = blockIdx.x * 64, i0 = blockIdx.y * 64, n = blockIdx.z;
  const int tid = threadIdx.x;
  __shared__ float Qs[64][68];  // [d][i]
  __shared__ float Ks[64][68];  // [d][j]
  const int lr = tid >> 4, lc = (tid & 15) * 4;
  float4 bias4 = *(const float4*)(qbias + n * DH + lc);
#pragma unroll
  for (int l = 0; l < 4; l++) {
    const int row = l * 16 + lr;
    float4 q4 = *(const float4*)(heads +
        ((size_t)(MLEN + i0 + row) * BSZ + b) * HC + n * DH + lc);
    Qs[lc + 0][row] = q4.x + bias4.x;
    Qs[lc + 1][row] = q4.y + bias4.y;
    Qs[lc + 2][row] = q4.z + bias4.z;
    Qs[lc + 3][row] = q4.w + bias4.w;
    float4 k4;
    if constexpr (PASS == 2)
      k4 = *(const float4*)(heads +
          ((size_t)(j0 + row) * BSZ + b) * HC + DM + n * DH + lc);
    else
      k4 = *(const float4*)(rkm + (size_t)(j0 + row) * DM + n * DH + lc);
    Ks[lc + 0][row] = k4.x;
    Ks[lc + 1][row] = k4.y;
    Ks[lc + 2][row] = k4.z;
    Ks[lc + 3][row] = k4.w;
  }
  __syncthreads();
  const int ti = (tid >> 4) * 4, tj = (tid & 15) * 4;
  float acc[4][4] = {};
#pragma unroll 8
  for (int d = 0; d < DH; d++) {
    float ra[4], rb[4];
    *(float4*)ra = *(const float4*)&Qs[d][ti];
    *(float4*)rb = *(const float4*)&Ks[d][tj];
#pragma unroll
    for (int r = 0; r < 4; r++)
#pragma unroll
      for (int c = 0; c < 4; c++) acc[r][c] = fmaf(ra[r], rb[c], acc[r][c]);
  }
#pragma unroll
  for (int r = 0; r < 4; r++) {
    const int i = i0 + ti + r;
#pragma unroll
    for (int c = 0; c < 4; c++) {
      const int j = j0 + tj + c;
      const size_t idx = ((size_t)n * QLEN + i) * KLEN + j;
      if constexpr (PASS == 1) {
        outp[idx] = acc[r][c];
      } else {
        float v;
        if (j > i + MLEN) {
          v = -INFINITY;
        } else {
          // rel_shift: BD[i,j] = BD_raw[i, j + MLEN-1 - i]; in-range for all
          // unmasked (i,j).
          v = (acc[r][c] +
               s2[((size_t)n * QLEN + i) * KLEN + (j + MLEN - 1 - i)]) * 0.125f;
        }
        outp[idx] = v;
      }
    }
  }
}

// ---------------- softmax over j (in place) + entropy ----------------
// grid (i 512, n 16), 256 threads, one float4/thread covers the 1024 row.
// -sum p log p = m + log L - (sum e*s)/L ; atomicAdd scaled mean into ent[n].
__global__ __launch_bounds__(256) void softmax_ent(
    float* __restrict__ score, float* __restrict__ ent) {
  const int i = blockIdx.x, n = blockIdx.y;
  const int tid = threadIdx.x;
  float* row = score + ((size_t)n * QLEN + i) * KLEN;
  float4 s4 = *(const float4*)(row + tid * 4);
  float ss[4] = {s4.x, s4.y, s4.z, s4.w};
  float m = fmaxf(fmaxf(ss[0], ss[1]), fmaxf(ss[2], ss[3]));
  __shared__ float redm[4];
  m = waveMax(m);
  if ((tid & 63) == 0) redm[tid >> 6] = m;
  __syncthreads();
  m = fmaxf(fmaxf(redm[0], redm[1]), fmaxf(redm[2], redm[3]));
  float ex[4], l = 0.f, es = 0.f;
#pragma unroll
  for (int t = 0; t < 4; t++) {
    ex[t] = expf(ss[t] - m);     // masked: exp(-inf) = 0 exactly
    l += ex[t];
    es += (ex[t] > 0.f) ? ex[t] * ss[t] : 0.f;  // guard 0 * -inf
  }
  __shared__ float2 red2[4];
  float2 p;
  p.x = waveSum(l);
  p.y = waveSum(es);
  if ((tid & 63) == 0) red2[tid >> 6] = p;
  __syncthreads();
  const float L = red2[0].x + red2[1].x + red2[2].x + red2[3].x;
  const float ES = red2[0].y + red2[1].y + red2[2].y + red2[3].y;
  const float inv = 1.f / L;
  float4 o;
  o.x = ex[0] * inv; o.y = ex[1] * inv; o.z = ex[2] * inv; o.w = ex[3] * inv;
  *(float4*)(row + tid * 4) = o;
  if (tid == 0)
    atomicAdd(ent + n, (m + logf(L) - ES * inv) * (1.f / (QLEN * BSZ)));
}

// ---------------- prob @ V per head ----------------
// grid (i-tile 8, head 16); per-b. M=512,N=64,K=1024; BM=64,BN=64,BK=16.
__global__ __launch_bounds__(256) void pv_kernel(
    const float* __restrict__ prob, const float* __restrict__ heads,
    float* __restrict__ attnb, int b) {
  const int i0 = blockIdx.x * 64, n = blockIdx.y;
  const int tid = threadIdx.x;
  __shared__ float As[16][68];  // [k][i] (transposed on store)
  __shared__ float Bs[16][68];  // [k][d]
  const int ar = tid >> 2, ac = (tid & 3) * 4;
  const int br = tid >> 4, bc = (tid & 15) * 4;
  const int ti = (tid >> 4) * 4, td = (tid & 15) * 4;
  float acc[4][4] = {};
  for (int k0 = 0; k0 < KLEN; k0 += 16) {
    float4 a4 = *(const float4*)(prob +
        ((size_t)n * QLEN + i0 + ar) * KLEN + k0 + ac);
    As[ac + 0][ar] = a4.x;
    As[ac + 1][ar] = a4.y;
    As[ac + 2][ar] = a4.z;
    As[ac + 3][ar] = a4.w;
    float4 v4 = *(const float4*)(heads +
        ((size_t)(k0 + br) * BSZ + b) * HC + 2 * DM + n * DH + bc);
    *(float4*)&Bs[br][bc] = v4;
    __syncthreads();
#pragma unroll
    for (int kk = 0; kk < 16; kk++) {
      float ra[4], rb[4];
      *(float4*)ra = *(const float4*)&As[kk][ti];
      *(float4*)rb = *(const float4*)&Bs[kk][td];
#pragma unroll
      for (int r = 0; r < 4; r++)
#pragma unroll
        for (int c = 0; c < 4; c++) acc[r][c] = fmaf(ra[r], rb[c], acc[r][c]);
    }
    __syncthreads();
  }
#pragma unroll
  for (int r = 0; r < 4; r++)
#pragma unroll
    for (int c = 0; c < 4; c++)
      attnb[((size_t)(i0 + ti + r) * BSZ + b) * DM + n * DH + td + c] =
          acc[r][c];
}

// ---------------- elementwise ----------------
__global__ __launch_bounds__(256) void ew_mul4(
    const float* __restrict__ a, const float* __restrict__ b,
    float* __restrict__ o) {
  const size_t idx = ((size_t)blockIdx.x * 256 + threadIdx.x) * 4;
  float4 x = *(const float4*)(a + idx);
  float4 y = *(const float4*)(b + idx);
  float4 r;
  r.x = x.x * y.x; r.y = x.y * y.y; r.z = x.z * y.z; r.w = x.w * y.w;
  *(float4*)(o + idx) = r;
}
// o = (1-z)*x + z*h
__global__ __launch_bounds__(256) void ew_gate4(
    const float* __restrict__ z, const float* __restrict__ x,
    const float* __restrict__ h, float* __restrict__ o) {
  const size_t idx = ((size_t)blockIdx.x * 256 + threadIdx.x) * 4;
  float4 zz = *(const float4*)(z + idx);
  float4 xx = *(const float4*)(x + idx);
  float4 hh = *(const float4*)(h + idx);
  float4 r;
  r.x = (1.f - zz.x) * xx.x + zz.x * hh.x;
  r.y = (1.f - zz.y) * xx.y + zz.y * hh.y;
  r.z = (1.f - zz.z) * xx.z + zz.z * hh.z;
  r.w = (1.f - zz.w) * xx.w + zz.w * hh.w;
  *(float4*)(o + idx) = r;
}

__global__ void zero16(float* p) {
  if (threadIdx.x < 16) p[threadIdx.x] = 0.f;
}

// ---------------------------------------------------------------------------
extern "C" void kernel_launch(void* const* d_in, const int* in_sizes, int n_in,
                              void* d_out, int out_size, void* d_ws,
                              size_t ws_size, hipStream_t stream) {
  (void)in_sizes; (void)n_in; (void)out_size; (void)ws_size;
  const float* w      = (const float*)d_in[0];
  const float* mems   = (const float*)d_in[1];
  const float* r      = (const float*)d_in[2];
  const float* rwb    = (const float*)d_in[3];
  const float* rrb    = (const float*)d_in[4];
  // d_in[5] attn_mask: deterministic (j > i+512), recomputed in-kernel.
  const float* ln_a_w = (const float*)d_in[6];
  const float* ln_a_b = (const float*)d_in[7];
  const float* W_qkv  = (const float*)d_in[8];
  const float* W_r    = (const float*)d_in[9];
  const float* W_o    = (const float*)d_in[10];
  const float* ln2_w  = (const float*)d_in[11];
  const float* ln2_b  = (const float*)d_in[12];
  const float* ff_W1  = (const float*)d_in[13];
  const float* ff_b1  = (const float*)d_in[14];
  const float* ff_W2  = (const float*)d_in[15];
  const float* ff_b2  = (const float*)d_in[16];
  const float* gm_Wr  = (const float*)d_in[17];
  const float* gm_Ur  = (const float*)d_in[18];
  const float* gm_Uz  = (const float*)d_in[19];
  const float* gm_Wg  = (const float*)d_in[20];
  const float* gm_Ug  = (const float*)d_in[21];
  const float* gm_Wz  = (const float*)d_in[22];
  const float* gm_bz  = (const float*)d_in[23];
  const float* gp_Wr  = (const float*)d_in[24];
  const float* gp_Ur  = (const float*)d_in[25];
  const float* gp_Uz  = (const float*)d_in[26];
  const float* gp_Wg  = (const float*)d_in[27];
  const float* gp_Ug  = (const float*)d_in[28];
  const float* gp_Wz  = (const float*)d_in[29];
  const float* gp_bz  = (const float*)d_in[30];

  float* out = (float*)d_out;
  float* ent = out + (size_t)QLEN * BSZ * DM;  // 16 floats after main output

  // ---- workspace arena (floats), peak ~189 MB with reuse ----
  float* ws    = (float*)d_ws;
  float* lncat = ws;                       // 4096*1024      [dead after QKV gemm]
  float* y     = lncat;                    // reuse: 2048*1024
  float* zg    = lncat + (size_t)NROWS * DM;  // reuse: 2048*1024
  float* heads = ws + (size_t)4194304;     // 4096*3072
  float* rk    = heads + (size_t)HR * HC;  // 1024*1024
  float* s2    = rk + (size_t)KLEN * DM;   // 16*512*1024 (per-b BD raw)
  float* score = s2 + (size_t)NH * QLEN * KLEN;   // 16*512*1024 (per-b)
  float* ffh   = score;                    // reuse after attention: 2048*4096
  float* attnb = score + (size_t)NH * QLEN * KLEN;  // 2048*1024
  float* lnb   = attnb;                    // reuse after W_o gemm
  float* rg    = attnb + (size_t)NROWS * DM;
  float* t1    = rg + (size_t)NROWS * DM;
  float* rx    = t1 + (size_t)NROWS * DM;
  float* o1    = rx + (size_t)NROWS * DM;
  float* ffo   = o1 + (size_t)NROWS * DM;

  // 1. LN over cat(mems, w) -> lncat (4096 x 1024)
  ln_kernel<true><<<HR, 256, 0, stream>>>(mems, w, ln_a_w, ln_a_b, lncat);
  // 2. heads = lncat @ W_qkv  (4096 x 3072)
  gemm_k<128, ACT_NONE, false, false><<<dim3(HC / 128, HR / 128), 256, 0,
      stream>>>(lncat, W_qkv, heads, nullptr, HR, HC, DM);
  // 3. rk = r @ W_r (1024 x 1024)
  gemm_k<64, ACT_NONE, false, false><<<dim3(DM / 128, KLEN / 64), 256, 0,
      stream>>>(r, W_r, rk, nullptr, KLEN, DM, DM);
  // 4. zero entropy accumulators
  zero16<<<1, 64, 0, stream>>>(ent);
  // 5. attention, per batch (buffers s2/score reused across b)
  for (int b = 0; b < BSZ; b++) {
    qk_kernel<1><<<dim3(16, 8, 16), 256, 0, stream>>>(heads, rk, rrb, s2,
                                                      nullptr, b);
    qk_kernel<2><<<dim3(16, 8, 16), 256, 0, stream>>>(heads, nullptr, rwb,
                                                      score, s2, b);
    softmax_ent<<<dim3(QLEN, NH), 256, 0, stream>>>(score, ent);
    pv_kernel<<<dim3(8, 16), 256, 0, stream>>>(score, heads, attnb, b);
  }
  // 6. y = relu(attn_out @ W_o)
  gemm_k<64, ACT_RELU, false, false><<<dim3(8, 32), 256, 0, stream>>>(
      attnb, W_o, y, nullptr, NROWS, DM, DM);
  // 7. GRU gate gm: x = w, y = y
  gemm_k<64, ACT_NONE, false, true><<<dim3(8, 32), 256, 0, stream>>>(
      y, gm_Wz, zg, gm_bz, NROWS, DM, DM);
  gemm_k<64, ACT_SIG, true, false><<<dim3(8, 32), 256, 0, stream>>>(
      w, gm_Uz, zg, nullptr, NROWS, DM, DM);
  gemm_k<64, ACT_NONE, false, false><<<dim3(8, 32), 256, 0, stream>>>(
      y, gm_Wr, rg, nullptr, NROWS, DM, DM);
  gemm_k<64, ACT_SIG, true, false><<<dim3(8, 32), 256, 0, stream>>>(
      w, gm_Ur, rg, nullptr, NROWS, DM, DM);
  ew_mul4<<<2048, 256, 0, stream>>>(rg, w, rx);  // rx = r * x
  gemm_k<64, ACT_NONE, false, false><<<dim3(8, 32), 256, 0, stream>>>(
      y, gm_Wg, t1, nullptr, NROWS, DM, DM);
  gemm_k<64, ACT_TANH, true, false><<<dim3(8, 32), 256, 0, stream>>>(
      rx, gm_Ug, t1, nullptr, NROWS, DM, DM);
  ew_gate4<<<2048, 256, 0, stream>>>(zg, w, t1, o1);  // o1 = (1-z)w + z h
  // 8. FF block
  ln_kernel<false><<<NROWS, 256, 0, stream>>>(o1, nullptr, ln2_w, ln2_b, lnb);
  gemm_k<128, ACT_RELU, false, true><<<dim3(DI / 128, NROWS / 128), 256, 0,
      stream>>>(lnb, ff_W1, ffh, ff_b1, NROWS, DI, DM);
  gemm_k<64, ACT_RELU, false, true><<<dim3(DM / 128, NROWS / 64), 256, 0,
      stream>>>(ffh, ff_W2, ffo, ff_b2, NROWS, DM, DI);
  // 9. GRU gate gp: x = o1, y = relu(ff) = ffo
  gemm_k<64, ACT_NONE, false, true><<<dim3(8, 32), 256, 0, stream>>>(
      ffo, gp_Wz, zg, gp_bz, NROWS, DM, DM);
  gemm_k<64, ACT_SIG, true, false><<<dim3(8, 32), 256, 0, stream>>>(
      o1, gp_Uz, zg, nullptr, NROWS, DM, DM);
  gemm_k<64, ACT_NONE, false, false><<<dim3(8, 32), 256, 0, stream>>>(
      ffo, gp_Wr, rg, nullptr, NROWS, DM, DM);
  gemm_k<64, ACT_SIG, true, false><<<dim3(8, 32), 256, 0, stream>>>(
      o1, gp_Ur, rg, nullptr, NROWS, DM, DM);
  ew_mul4<<<2048, 256, 0, stream>>>(rg, o1, rx);
  gemm_k<64, ACT_NONE, false, false><<<dim3(8, 32), 256, 0, stream>>>(
      ffo, gp_Wg, t1, nullptr, NROWS, DM, DM);
  gemm_k<64, ACT_TANH, true, false><<<dim3(8, 32), 256, 0, stream>>>(
      rx, gp_Ug, t1, nullptr, NROWS, DM, DM);
  ew_gate4<<<2048, 256, 0, stream>>>(zg, o1, t1, out);  // final output
}

// Round 2
// 1552.760 us; speedup vs baseline: 2.6213x; 2.6213x over previous
//
#include <hip/hip_runtime.h>
#include <math.h>

// ---------------------------------------------------------------------------
// Transformer-XL RelPartialLearnableDecoderLayer.
// Round 2: all projection/gate/FF GEMMs on bf16 MFMA (m97 structure:
// 128x128 tile, BK=32, global_load_lds width=16). Attention stays fp32.
// qlen=512 mlen=512 klen=1024 bsz=4 d_model=1024 d_inner=4096 nh=16 dh=64
// rel_shift closed form: BD[i,j] = BD_raw[i, j+511-i]; mask j > i+512.
// ---------------------------------------------------------------------------

#define QLEN 512
#define MLEN 512
#define KLEN 1024
#define BSZ  4
#define DM   1024
#define DI   4096
#define NH   16
#define DH   64
#define HC   (3*DM)
#define HR   (KLEN*BSZ)   // 4096
#define NROWS (QLEN*BSZ)  // 2048

enum { ACT_NONE = 0, ACT_RELU = 1, ACT_SIG = 2, ACT_TANH = 3 };

using short8 = __attribute__((ext_vector_type(8))) short;
using f32x4  = __attribute__((ext_vector_type(4))) float;

__device__ __forceinline__ unsigned short f2bf(float f) {
  union { float f; unsigned u; } v;
  v.f = f;
  unsigned r = v.u + 0x7FFFu + ((v.u >> 16) & 1u);  // RNE
  return (unsigned short)(r >> 16);
}

__device__ __forceinline__ void async16(const void* g, void* l) {
  __builtin_amdgcn_global_load_lds(
      (const __attribute__((address_space(1))) void*)g,
      (__attribute__((address_space(3))) void*)l, 16, 0, 0);
}

__device__ __forceinline__ float waveSum(float v) {
#pragma unroll
  for (int o = 32; o; o >>= 1) v += __shfl_down(v, o, 64);
  return v;
}
__device__ __forceinline__ float waveMax(float v) {
#pragma unroll
  for (int o = 32; o; o >>= 1) v = fmaxf(v, __shfl_down(v, o, 64));
  return v;
}

// ---------------- LayerNorm -> bf16 or fp32 ----------------
template <bool CONCAT, bool OUT16>
__global__ __launch_bounds__(256) void ln_kernel(
    const float* __restrict__ a, const float* __restrict__ a2,
    const float* __restrict__ wt, const float* __restrict__ bs,
    void* __restrict__ dstv) {
  const int row = blockIdx.x;
  const int tid = threadIdx.x;
  const float* srow;
  if (CONCAT)
    srow = (row < MLEN * BSZ) ? a + (size_t)row * DM
                              : a2 + (size_t)(row - MLEN * BSZ) * DM;
  else
    srow = a + (size_t)row * DM;
  float4 x = *(const float4*)(srow + tid * 4);
  float s = x.x + x.y + x.z + x.w;
  float q = x.x * x.x + x.y * x.y + x.z * x.z + x.w * x.w;
  __shared__ float2 red[4];
  float2 p;
  p.x = waveSum(s);
  p.y = waveSum(q);
  if ((tid & 63) == 0) red[tid >> 6] = p;
  __syncthreads();
  float S = red[0].x + red[1].x + red[2].x + red[3].x;
  float Q = red[0].y + red[1].y + red[2].y + red[3].y;
  const float inv = 1.0f / DM;
  float mu = S * inv;
  float var = Q * inv - mu * mu;
  float rs = rsqrtf(var + 1e-5f);
  float4 w4 = *(const float4*)(wt + tid * 4);
  float4 b4 = *(const float4*)(bs + tid * 4);
  float o0 = (x.x - mu) * rs * w4.x + b4.x;
  float o1 = (x.y - mu) * rs * w4.y + b4.y;
  float o2 = (x.z - mu) * rs * w4.z + b4.z;
  float o3 = (x.w - mu) * rs * w4.w + b4.w;
  if constexpr (OUT16) {
    ushort4 o = {f2bf(o0), f2bf(o1), f2bf(o2), f2bf(o3)};
    *(ushort4*)((unsigned short*)dstv + (size_t)row * DM + tid * 4) = o;
  } else {
    float4 o = {o0, o1, o2, o3};
    *(float4*)((float*)dstv + (size_t)row * DM + tid * 4) = o;
  }
}

// ---------------- bf16 MFMA GEMM:  C = act(A @ Bt^T [+bias]) ---------------
// A: M x K bf16 row-major (lda == K).  Bt: N x K bf16 row-major (B^T).
// 128x128 block tile, BK=32, 256 thr = 4 waves (2x2 of 64x64), m97 layout.
template <int ACT, bool BIAS, bool OUT16>
__global__ __launch_bounds__(256) void mgemm(
    const unsigned short* __restrict__ A, const unsigned short* __restrict__ Bt,
    void* __restrict__ Cv, const float* __restrict__ bias,
    int M, int N, int K, int ldc) {
  (void)M; (void)N;
  __shared__ __align__(16) unsigned short As[128][32];
  __shared__ __align__(16) unsigned short Bs[128][32];
  const int tid = threadIdx.x;
  const int wave = tid >> 6, lane = tid & 63;
  const int row0 = blockIdx.y * 128, col0 = blockIdx.x * 128;
  const int wm = (wave >> 1) * 64, wn = (wave & 1) * 64;
  const int lr = lane & 15, quad = lane >> 4;

  // staging: lane covers (row = wave*32 + i*16 + lane/4, col = (lane&3)*8)
  const int srow = wave * 32 + (lane >> 2);
  const int scol = (lane & 3) * 8;
  const unsigned short* ga = A + (size_t)(row0 + srow) * K + scol;
  const unsigned short* gb = Bt + (size_t)(col0 + srow) * K + scol;
  unsigned short* la0 = &As[wave * 32][0];
  unsigned short* la1 = &As[wave * 32 + 16][0];
  unsigned short* lb0 = &Bs[wave * 32][0];
  unsigned short* lb1 = &Bs[wave * 32 + 16][0];
  const size_t rstep = (size_t)16 * K;

  f32x4 acc[4][4];
#pragma unroll
  for (int a = 0; a < 4; a++)
#pragma unroll
    for (int b = 0; b < 4; b++) {
      acc[a][b][0] = 0.f; acc[a][b][1] = 0.f;
      acc[a][b][2] = 0.f; acc[a][b][3] = 0.f;
    }

  for (int k0 = 0; k0 < K; k0 += 32) {
    __syncthreads();
    async16(ga, la0);
    async16(ga + rstep, la1);
    async16(gb, lb0);
    async16(gb + rstep, lb1);
    ga += 32;
    gb += 32;
    __syncthreads();
    short8 af[4], bf[4];
#pragma unroll
    for (int mi = 0; mi < 4; mi++)
      af[mi] = *(const short8*)&As[wm + mi * 16 + lr][quad * 8];
#pragma unroll
    for (int ni = 0; ni < 4; ni++)
      bf[ni] = *(const short8*)&Bs[wn + ni * 16 + lr][quad * 8];
#pragma unroll
    for (int mi = 0; mi < 4; mi++)
#pragma unroll
      for (int ni = 0; ni < 4; ni++)
        acc[mi][ni] = __builtin_amdgcn_mfma_f32_16x16x32_bf16(
            af[mi], bf[ni], acc[mi][ni], 0, 0, 0);
  }

  const int cbase = col0 + wn + lr;
  float bv[4];
  if constexpr (BIAS) {
#pragma unroll
    for (int ni = 0; ni < 4; ni++) bv[ni] = bias[cbase + ni * 16];
  }
#pragma unroll
  for (int mi = 0; mi < 4; mi++) {
    const int r0 = row0 + wm + mi * 16 + quad * 4;
#pragma unroll
    for (int ni = 0; ni < 4; ni++) {
      const int cc = cbase + ni * 16;
#pragma unroll
      for (int e = 0; e < 4; e++) {
        float v = acc[mi][ni][e];
        if constexpr (BIAS) v += bv[ni];
        if constexpr (ACT == ACT_RELU) v = fmaxf(v, 0.f);
        else if constexpr (ACT == ACT_SIG) v = 1.f / (1.f + expf(-v));
        else if constexpr (ACT == ACT_TANH) v = tanhf(v);
        if constexpr (OUT16)
          ((unsigned short*)Cv)[(size_t)(r0 + e) * ldc + cc] = f2bf(v);
        else
          ((float*)Cv)[(size_t)(r0 + e) * ldc + cc] = v;
      }
    }
  }
}

// ---------------- weight cast+transpose: dst[n][k] = bf16(src[k][n]) -------
__global__ __launch_bounds__(256) void castT(
    const float* __restrict__ src, int K, int N,
    unsigned short* __restrict__ dst, int dstStride, int colOff) {
  (void)K;
  __shared__ float T[64][65];
  const int tid = threadIdx.x;
  const int n0 = blockIdx.x * 64, k0 = blockIdx.y * 64;
  const int tx = tid & 15, ty = tid >> 4;
#pragma unroll
  for (int l = 0; l < 4; l++) {
    const int k = ty + l * 16;
    float4 v = *(const float4*)(src + (size_t)(k0 + k) * N + n0 + tx * 4);
    T[tx * 4 + 0][k] = v.x;
    T[tx * 4 + 1][k] = v.y;
    T[tx * 4 + 2][k] = v.z;
    T[tx * 4 + 3][k] = v.w;
  }
  __syncthreads();
#pragma unroll
  for (int l = 0; l < 4; l++) {
    const int n = ty + l * 16;
    ushort4 o = {f2bf(T[n][tx * 4 + 0]), f2bf(T[n][tx * 4 + 1]),
                 f2bf(T[n][tx * 4 + 2]), f2bf(T[n][tx * 4 + 3])};
    *(ushort4*)(dst + (size_t)(n0 + n) * dstStride + colOff + k0 + tx * 4) = o;
  }
}

// ---------------- fp32 -> bf16 row cast (cols = 1024, strided dst) ---------
__global__ __launch_bounds__(256) void castRows(
    const float* __restrict__ src, unsigned short* __restrict__ dst,
    int dstStride) {
  const size_t e0 = ((size_t)blockIdx.x * 256 + threadIdx.x) * 4;
  const size_t m = e0 >> 10, c = e0 & 1023;
  float4 v = *(const float4*)(src + e0);
  ushort4 o = {f2bf(v.x), f2bf(v.y), f2bf(v.z), f2bf(v.w)};
  *(ushort4*)(dst + m * dstStride + c) = o;
}

// ---------------- QK^T batched per head (fp32), K=64 ----------------
template <int PASS>
__global__ __launch_bounds__(256) void qk_kernel(
    const float* __restrict__ heads, const float* __restrict__ rkm,
    const float* __restrict__ qbias, float* __restrict__ outp,
    const float* __restrict__ s2, int b) {
  const int j0 = blockIdx.x * 64, i0 = blockIdx.y * 64, n = blockIdx.z;
  const int tid = threadIdx.x;
  __shared__ float Qs[64][68];
  __shared__ float Ks[64][68];
  const int lr = tid >> 4, lc = (tid & 15) * 4;
  float4 bias4 = *(const float4*)(qbias + n * DH + lc);
#pragma unroll
  for (int l = 0; l < 4; l++) {
    const int row = l * 16 + lr;
    float4 q4 = *(const float4*)(heads +
        ((size_t)(MLEN + i0 + row) * BSZ + b) * HC + n * DH + lc);
    Qs[lc + 0][row] = q4.x + bias4.x;
    Qs[lc + 1][row] = q4.y + bias4.y;
    Qs[lc + 2][row] = q4.z + bias4.z;
    Qs[lc + 3][row] = q4.w + bias4.w;
    float4 k4;
    if constexpr (PASS == 2)
      k4 = *(const float4*)(heads +
          ((size_t)(j0 + row) * BSZ + b) * HC + DM + n * DH + lc);
    else
      k4 = *(const float4*)(rkm + (size_t)(j0 + row) * DM + n * DH + lc);
    Ks[lc + 0][row] = k4.x;
    Ks[lc + 1][row] = k4.y;
    Ks[lc + 2][row] = k4.z;
    Ks[lc + 3][row] = k4.w;
  }
  __syncthreads();
  const int ti = (tid >> 4) * 4, tj = (tid & 15) * 4;
  float acc[4][4] = {};
#pragma unroll 8
  for (int d = 0; d < DH; d++) {
    float ra[4], rb[4];
    *(float4*)ra = *(const float4*)&Qs[d][ti];
    *(float4*)rb = *(const float4*)&Ks[d][tj];
#pragma unroll
    for (int r = 0; r < 4; r++)
#pragma unroll
      for (int c = 0; c < 4; c++) acc[r][c] = fmaf(ra[r], rb[c], acc[r][c]);
  }
#pragma unroll
  for (int r = 0; r < 4; r++) {
    const int i = i0 + ti + r;
#pragma unroll
    for (int c = 0; c < 4; c++) {
      const int j = j0 + tj + c;
      const size_t idx = ((size_t)n * QLEN + i) * KLEN + j;
      if constexpr (PASS == 1) {
        outp[idx] = acc[r][c];
      } else {
        float v;
        if (j > i + MLEN) {
          v = -INFINITY;
        } else {
          v = (acc[r][c] +
               s2[((size_t)n * QLEN + i) * KLEN + (j + MLEN - 1 - i)]) * 0.125f;
        }
        outp[idx] = v;
      }
    }
  }
}

// ---------------- softmax over j (in place) + entropy ----------------
__global__ __launch_bounds__(256) void softmax_ent(
    float* __restrict__ score, float* __restrict__ ent) {
  const int i = blockIdx.x, n = blockIdx.y;
  const int tid = threadIdx.x;
  float* row = score + ((size_t)n * QLEN + i) * KLEN;
  float4 s4 = *(const float4*)(row + tid * 4);
  float ss[4] = {s4.x, s4.y, s4.z, s4.w};
  float m = fmaxf(fmaxf(ss[0], ss[1]), fmaxf(ss[2], ss[3]));
  __shared__ float redm[4];
  m = waveMax(m);
  if ((tid & 63) == 0) redm[tid >> 6] = m;
  __syncthreads();
  m = fmaxf(fmaxf(redm[0], redm[1]), fmaxf(redm[2], redm[3]));
  float ex[4], l = 0.f, es = 0.f;
#pragma unroll
  for (int t = 0; t < 4; t++) {
    ex[t] = expf(ss[t] - m);
    l += ex[t];
    es += (ex[t] > 0.f) ? ex[t] * ss[t] : 0.f;
  }
  __shared__ float2 red2[4];
  float2 p;
  p.x = waveSum(l);
  p.y = waveSum(es);
  if ((tid & 63) == 0) red2[tid >> 6] = p;
  __syncthreads();
  const float L = red2[0].x + red2[1].x + red2[2].x + red2[3].x;
  const float ES = red2[0].y + red2[1].y + red2[2].y + red2[3].y;
  const float inv = 1.f / L;
  float4 o;
  o.x = ex[0] * inv; o.y = ex[1] * inv; o.z = ex[2] * inv; o.w = ex[3] * inv;
  *(float4*)(row + tid * 4) = o;
  if (tid == 0)
    atomicAdd(ent + n, (m + logf(L) - ES * inv) * (1.f / (QLEN * BSZ)));
}

// ---------------- prob @ V per head (fp32 in, bf16 out) ----------------
__global__ __launch_bounds__(256) void pv_kernel(
    const float* __restrict__ prob, const float* __restrict__ heads,
    unsigned short* __restrict__ attnb, int b) {
  const int i0 = blockIdx.x * 64, n = blockIdx.y;
  const int tid = threadIdx.x;
  __shared__ float As[16][68];
  __shared__ float Bs[16][68];
  const int ar = tid >> 2, ac = (tid & 3) * 4;
  const int br = tid >> 4, bc = (tid & 15) * 4;
  const int ti = (tid >> 4) * 4, td = (tid & 15) * 4;
  float acc[4][4] = {};
  for (int k0 = 0; k0 < KLEN; k0 += 16) {
    float4 a4 = *(const float4*)(prob +
        ((size_t)n * QLEN + i0 + ar) * KLEN + k0 + ac);
    As[ac + 0][ar] = a4.x;
    As[ac + 1][ar] = a4.y;
    As[ac + 2][ar] = a4.z;
    As[ac + 3][ar] = a4.w;
    float4 v4 = *(const float4*)(heads +
        ((size_t)(k0 + br) * BSZ + b) * HC + 2 * DM + n * DH + bc);
    *(float4*)&Bs[br][bc] = v4;
    __syncthreads();
#pragma unroll
    for (int kk = 0; kk < 16; kk++) {
      float ra[4], rb[4];
      *(float4*)ra = *(const float4*)&As[kk][ti];
      *(float4*)rb = *(const float4*)&Bs[kk][td];
#pragma unroll
      for (int r = 0; r < 4; r++)
#pragma unroll
        for (int c = 0; c < 4; c++) acc[r][c] = fmaf(ra[r], rb[c], acc[r][c]);
    }
    __syncthreads();
  }
#pragma unroll
  for (int r = 0; r < 4; r++)
#pragma unroll
    for (int c = 0; c < 4; c++)
      attnb[((size_t)(i0 + ti + r) * BSZ + b) * DM + n * DH + td + c] =
          f2bf(acc[r][c]);
}

// ---------------- elementwise ----------------
// rx = r * x -> bf16 into Ayx[:, 1024:2048]
__global__ __launch_bounds__(256) void ew_rx(
    const float* __restrict__ zr, const float* __restrict__ x,
    unsigned short* __restrict__ ayx) {
  const size_t e0 = ((size_t)blockIdx.x * 256 + threadIdx.x) * 4;
  const size_t m = e0 >> 10, c = e0 & 1023;
  float4 rr = *(const float4*)(zr + m * 2048 + 1024 + c);
  float4 xx = *(const float4*)(x + e0);
  ushort4 o = {f2bf(rr.x * xx.x), f2bf(rr.y * xx.y),
               f2bf(rr.z * xx.z), f2bf(rr.w * xx.w)};
  *(ushort4*)(ayx + m * 2048 + 1024 + c) = o;
}
// o = (1-z)*x + z*h  (z from zr[:,0:1024])
__global__ __launch_bounds__(256) void ew_out(
    const float* __restrict__ zr, const float* __restrict__ x,
    const float* __restrict__ h, float* __restrict__ o) {
  const size_t e0 = ((size_t)blockIdx.x * 256 + threadIdx.x) * 4;
  const size_t m = e0 >> 10, c = e0 & 1023;
  float4 zz = *(const float4*)(zr + m * 2048 + c);
  float4 xx = *(const float4*)(x + e0);
  float4 hh = *(const float4*)(h + e0);
  float4 r;
  r.x = (1.f - zz.x) * xx.x + zz.x * hh.x;
  r.y = (1.f - zz.y) * xx.y + zz.y * hh.y;
  r.z = (1.f - zz.z) * xx.z + zz.z * hh.z;
  r.w = (1.f - zz.w) * xx.w + zz.w * hh.w;
  *(float4*)(o + e0) = r;
}

__global__ void fill_bias(const float* __restrict__ b, float* __restrict__ d) {
  const int i = blockIdx.x * 256 + threadIdx.x;
  if (i < 2048) d[i] = (i < 1024) ? b[i] : 0.f;
}
__global__ void zero16(float* p) {
  if (threadIdx.x < 16) p[threadIdx.x] = 0.f;
}

// ---------------------------------------------------------------------------
extern "C" void kernel_launch(void* const* d_in, const int* in_sizes, int n_in,
                              void* d_out, int out_size, void* d_ws,
                              size_t ws_size, hipStream_t stream) {
  (void)in_sizes; (void)n_in; (void)out_size; (void)ws_size;
  const float* w      = (const float*)d_in[0];
  const float* mems   = (const float*)d_in[1];
  const float* r      = (const float*)d_in[2];
  const float* rwb    = (const float*)d_in[3];
  const float* rrb    = (const float*)d_in[4];
  const float* ln_a_w = (const float*)d_in[6];
  const float* ln_a_b = (const float*)d_in[7];
  const float* W_qkv  = (const float*)d_in[8];
  const float* W_r    = (const float*)d_in[9];
  const float* W_o    = (const float*)d_in[10];
  const float* ln2_w  = (const float*)d_in[11];
  const float* ln2_b  = (const float*)d_in[12];
  const float* ff_W1  = (const float*)d_in[13];
  const float* ff_b1  = (const float*)d_in[14];
  const float* ff_W2  = (const float*)d_in[15];
  const float* ff_b2  = (const float*)d_in[16];
  const float* gm_Wr  = (const float*)d_in[17];
  const float* gm_Ur  = (const float*)d_in[18];
  const float* gm_Uz  = (const float*)d_in[19];
  const float* gm_Wg  = (const float*)d_in[20];
  const float* gm_Ug  = (const float*)d_in[21];
  const float* gm_Wz  = (const float*)d_in[22];
  const float* gm_bz  = (const float*)d_in[23];
  const float* gp_Wr  = (const float*)d_in[24];
  const float* gp_Ur  = (const float*)d_in[25];
  const float* gp_Uz  = (const float*)d_in[26];
  const float* gp_Wg  = (const float*)d_in[27];
  const float* gp_Ug  = (const float*)d_in[28];
  const float* gp_Wz  = (const float*)d_in[29];
  const float* gp_bz  = (const float*)d_in[30];

  float* out = (float*)d_out;
  float* ent = out + (size_t)NROWS * DM;

  // ---- workspace carve (bytes) ----
  char* base = (char*)d_ws;
  size_t o = 0;
  unsigned short* wt_qkv   = (unsigned short*)(base + o); o += (size_t)3072 * 1024 * 2;
  unsigned short* wt_r     = (unsigned short*)(base + o); o += (size_t)1024 * 1024 * 2;
  unsigned short* wt_o     = (unsigned short*)(base + o); o += (size_t)1024 * 1024 * 2;
  unsigned short* wt_gm_zr = (unsigned short*)(base + o); o += (size_t)2048 * 2048 * 2;
  unsigned short* wt_gm_g  = (unsigned short*)(base + o); o += (size_t)1024 * 2048 * 2;
  unsigned short* wt_gp_zr = (unsigned short*)(base + o); o += (size_t)2048 * 2048 * 2;
  unsigned short* wt_gp_g  = (unsigned short*)(base + o); o += (size_t)1024 * 2048 * 2;
  unsigned short* wt_ff1   = (unsigned short*)(base + o); o += (size_t)4096 * 1024 * 2;
  unsigned short* wt_ff2   = (unsigned short*)(base + o); o += (size_t)1024 * 4096 * 2;
  float* bias_gm = (float*)(base + o); o += 2048 * 4;
  float* bias_gp = (float*)(base + o); o += 2048 * 4;
  // heads region (fp32 heads; after attention overlaid with gate temps)
  char* hreg = base + o;  o += (size_t)HR * HC * 4;            // 50.3 MB
  float* heads = (float*)hreg;
  unsigned short* Ayx = (unsigned short*)hreg;                 // 8.39 MB
  float* zr   = (float*)(hreg + 8388608);                      // 16.8 MB
  float* hbuf = (float*)(hreg + 25165824);                     // 8.39 MB
  float* o1   = (float*)(hreg + 33554432);                     // 8.39 MB
  float* s2   = (float*)(base + o); o += (size_t)NH * QLEN * KLEN * 4;
  char* sreg = base + o;  o += (size_t)NH * QLEN * KLEN * 4;   // score region
  float* score = (float*)sreg;
  unsigned short* ffh_bf = (unsigned short*)sreg;              // 16.8 MB
  unsigned short* attnb_bf = (unsigned short*)(base + o); o += (size_t)NROWS * DM * 2;
  char* misc = base + o;  o += 8388608;                        // 8.39 MB
  unsigned short* lncat_bf = (unsigned short*)misc;
  unsigned short* r_bf = (unsigned short*)misc;
  float* rk = (float*)(misc + 2097152);
  unsigned short* lnb_bf = (unsigned short*)misc;

  // ---- phase 0: weight cast/transpose + biases ----
  castT<<<dim3(48, 16), 256, 0, stream>>>(W_qkv, 1024, 3072, wt_qkv, 1024, 0);
  castT<<<dim3(16, 16), 256, 0, stream>>>(W_r, 1024, 1024, wt_r, 1024, 0);
  castT<<<dim3(16, 16), 256, 0, stream>>>(W_o, 1024, 1024, wt_o, 1024, 0);
  castT<<<dim3(16, 16), 256, 0, stream>>>(gm_Wz, 1024, 1024, wt_gm_zr, 2048, 0);
  castT<<<dim3(16, 16), 256, 0, stream>>>(gm_Uz, 1024, 1024, wt_gm_zr, 2048, 1024);
  castT<<<dim3(16, 16), 256, 0, stream>>>(gm_Wr, 1024, 1024, wt_gm_zr + (size_t)1024 * 2048, 2048, 0);
  castT<<<dim3(16, 16), 256, 0, stream>>>(gm_Ur, 1024, 1024, wt_gm_zr + (size_t)1024 * 2048, 2048, 1024);
  castT<<<dim3(16, 16), 256, 0, stream>>>(gm_Wg, 1024, 1024, wt_gm_g, 2048, 0);
  castT<<<dim3(16, 16), 256, 0, stream>>>(gm_Ug, 1024, 1024, wt_gm_g, 2048, 1024);
  castT<<<dim3(16, 16), 256, 0, stream>>>(gp_Wz, 1024, 1024, wt_gp_zr, 2048, 0);
  castT<<<dim3(16, 16), 256, 0, stream>>>(gp_Uz, 1024, 1024, wt_gp_zr, 2048, 1024);
  castT<<<dim3(16, 16), 256, 0, stream>>>(gp_Wr, 1024, 1024, wt_gp_zr + (size_t)1024 * 2048, 2048, 0);
  castT<<<dim3(16, 16), 256, 0, stream>>>(gp_Ur, 1024, 1024, wt_gp_zr + (size_t)1024 * 2048, 2048, 1024);
  castT<<<dim3(16, 16), 256, 0, stream>>>(gp_Wg, 1024, 1024, wt_gp_g, 2048, 0);
  castT<<<dim3(16, 16), 256, 0, stream>>>(gp_Ug, 1024, 1024, wt_gp_g, 2048, 1024);
  castT<<<dim3(64, 16), 256, 0, stream>>>(ff_W1, 1024, 4096, wt_ff1, 1024, 0);
  castT<<<dim3(16, 64), 256, 0, stream>>>(ff_W2, 4096, 1024, wt_ff2, 4096, 0);
  fill_bias<<<8, 256, 0, stream>>>(gm_bz, bias_gm);
  fill_bias<<<8, 256, 0, stream>>>(gp_bz, bias_gp);
  zero16<<<1, 64, 0, stream>>>(ent);

  // ---- phase 1: LN + QKV / r projections ----
  ln_kernel<true, true><<<HR, 256, 0, stream>>>(mems, w, ln_a_w, ln_a_b, lncat_bf);
  mgemm<ACT_NONE, false, false><<<dim3(24, 32), 256, 0, stream>>>(
      lncat_bf, wt_qkv, heads, nullptr, HR, HC, 1024, HC);
  castRows<<<1024, 256, 0, stream>>>(r, r_bf, 1024);
  mgemm<ACT_NONE, false, false><<<dim3(8, 8), 256, 0, stream>>>(
      r_bf, wt_r, rk, nullptr, 1024, 1024, 1024, 1024);

  // ---- phase 2: attention per batch ----
  for (int b = 0; b < BSZ; b++) {
    qk_kernel<1><<<dim3(16, 8, 16), 256, 0, stream>>>(heads, rk, rrb, s2,
                                                      nullptr, b);
    qk_kernel<2><<<dim3(16, 8, 16), 256, 0, stream>>>(heads, nullptr, rwb,
                                                      score, s2, b);
    softmax_ent<<<dim3(QLEN, NH), 256, 0, stream>>>(score, ent);
    pv_kernel<<<dim3(8, 16), 256, 0, stream>>>(score, heads, attnb_bf, b);
  }

  // ---- phase 3: W_o + gm GRU gate (heads now dead; overlays live) ----
  mgemm<ACT_RELU, false, true><<<dim3(8, 16), 256, 0, stream>>>(
      attnb_bf, wt_o, Ayx, nullptr, NROWS, 1024, 1024, 2048);   // y -> Ayx[:,0:1024]
  castRows<<<2048, 256, 0, stream>>>(w, Ayx + 1024, 2048);      // x -> Ayx[:,1024:]
  mgemm<ACT_SIG, true, false><<<dim3(16, 16), 256, 0, stream>>>(
      Ayx, wt_gm_zr, zr, bias_gm, NROWS, 2048, 2048, 2048);
  ew_rx<<<2048, 256, 0, stream>>>(zr, w, Ayx);
  mgemm<ACT_TANH, false, false><<<dim3(8, 16), 256, 0, stream>>>(
      Ayx, wt_gm_g, hbuf, nullptr, NROWS, 1024, 2048, 1024);
  ew_out<<<2048, 256, 0, stream>>>(zr, w, hbuf, o1);

  // ---- phase 4: FF ----
  ln_kernel<false, true><<<NROWS, 256, 0, stream>>>(o1, nullptr, ln2_w, ln2_b,
                                                    lnb_bf);
  mgemm<ACT_RELU, true, true><<<dim3(32, 16), 256, 0, stream>>>(
      lnb_bf, wt_ff1, ffh_bf, ff_b1, NROWS, DI, 1024, DI);
  mgemm<ACT_RELU, true, true><<<dim3(8, 16), 256, 0, stream>>>(
      ffh_bf, wt_ff2, Ayx, ff_b2, NROWS, 1024, DI, 2048);       // ffo -> Ayx[:,0:1024]
  castRows<<<2048, 256, 0, stream>>>(o1, Ayx + 1024, 2048);     // x=o1 -> Ayx[:,1024:]

  // ---- phase 5: gp GRU gate ----
  mgemm<ACT_SIG, true, false><<<dim3(16, 16), 256, 0, stream>>>(
      Ayx, wt_gp_zr, zr, bias_gp, NROWS, 2048, 2048, 2048);
  ew_rx<<<2048, 256, 0, stream>>>(zr, o1, Ayx);
  mgemm<ACT_TANH, false, false><<<dim3(8, 16), 256, 0, stream>>>(
      Ayx, wt_gp_g, hbuf, nullptr, NROWS, 1024, 2048, 1024);
  ew_out<<<2048, 256, 0, stream>>>(zr, o1, hbuf, out);
}

// Round 3
// 767.872 us; speedup vs baseline: 5.3007x; 2.0222x over previous
//
#include <hip/hip_runtime.h>
#include <math.h>

// ---------------------------------------------------------------------------
// Transformer-XL RelPartialLearnableDecoderLayer.
// Round 3: GEMMs on bf16 MFMA (m97 structure) + fully fused flash-style
// MFMA attention (AC + rel-shifted BD + online softmax + entropy + PV in one
// kernel; score matrix never materialized).
// rel_shift closed form: BD[i,j] = BD_raw[i, j+511-i]; mask j > i+512.
// ---------------------------------------------------------------------------

#define QLEN 512
#define MLEN 512
#define KLEN 1024
#define BSZ  4
#define DM   1024
#define DI   4096
#define NH   16
#define DH   64
#define HC   (3*DM)
#define HR   (KLEN*BSZ)   // 4096
#define NROWS (QLEN*BSZ)  // 2048

enum { ACT_NONE = 0, ACT_RELU = 1, ACT_SIG = 2, ACT_TANH = 3 };

using short8 = __attribute__((ext_vector_type(8))) short;
using f32x4  = __attribute__((ext_vector_type(4))) float;

__device__ __forceinline__ unsigned short f2bf(float f) {
  union { float f; unsigned u; } v;
  v.f = f;
  unsigned r = v.u + 0x7FFFu + ((v.u >> 16) & 1u);  // RNE
  return (unsigned short)(r >> 16);
}
__device__ __forceinline__ float bf2f(unsigned short u) {
  union { unsigned u; float f; } v;
  v.u = ((unsigned)u) << 16;
  return v.f;
}

__device__ __forceinline__ void async16(const void* g, void* l) {
  __builtin_amdgcn_global_load_lds(
      (const __attribute__((address_space(1))) void*)g,
      (__attribute__((address_space(3))) void*)l, 16, 0, 0);
}

__device__ __forceinline__ float waveSum(float v) {
#pragma unroll
  for (int o = 32; o; o >>= 1) v += __shfl_down(v, o, 64);
  return v;
}

// ---------------- LayerNorm -> bf16 ----------------
template <bool CONCAT>
__global__ __launch_bounds__(256) void ln_kernel(
    const float* __restrict__ a, const float* __restrict__ a2,
    const float* __restrict__ wt, const float* __restrict__ bs,
    unsigned short* __restrict__ dst) {
  const int row = blockIdx.x;
  const int tid = threadIdx.x;
  const float* srow;
  if (CONCAT)
    srow = (row < MLEN * BSZ) ? a + (size_t)row * DM
                              : a2 + (size_t)(row - MLEN * BSZ) * DM;
  else
    srow = a + (size_t)row * DM;
  float4 x = *(const float4*)(srow + tid * 4);
  float s = x.x + x.y + x.z + x.w;
  float q = x.x * x.x + x.y * x.y + x.z * x.z + x.w * x.w;
  __shared__ float2 red[4];
  float2 p;
  p.x = waveSum(s);
  p.y = waveSum(q);
  if ((tid & 63) == 0) red[tid >> 6] = p;
  __syncthreads();
  float S = red[0].x + red[1].x + red[2].x + red[3].x;
  float Q = red[0].y + red[1].y + red[2].y + red[3].y;
  const float inv = 1.0f / DM;
  float mu = S * inv;
  float var = Q * inv - mu * mu;
  float rs = rsqrtf(var + 1e-5f);
  float4 w4 = *(const float4*)(wt + tid * 4);
  float4 b4 = *(const float4*)(bs + tid * 4);
  ushort4 o = {f2bf((x.x - mu) * rs * w4.x + b4.x),
               f2bf((x.y - mu) * rs * w4.y + b4.y),
               f2bf((x.z - mu) * rs * w4.z + b4.z),
               f2bf((x.w - mu) * rs * w4.w + b4.w)};
  *(ushort4*)(dst + (size_t)row * DM + tid * 4) = o;
}

// ---------------- bf16 MFMA GEMM:  C = act(A @ Bt^T [+bias]) ---------------
template <int ACT, bool BIAS, bool OUT16>
__global__ __launch_bounds__(256) void mgemm(
    const unsigned short* __restrict__ A, const unsigned short* __restrict__ Bt,
    void* __restrict__ Cv, const float* __restrict__ bias,
    int M, int N, int K, int ldc) {
  (void)M; (void)N;
  __shared__ __align__(16) unsigned short As[128][32];
  __shared__ __align__(16) unsigned short Bs[128][32];
  const int tid = threadIdx.x;
  const int wave = tid >> 6, lane = tid & 63;
  const int row0 = blockIdx.y * 128, col0 = blockIdx.x * 128;
  const int wm = (wave >> 1) * 64, wn = (wave & 1) * 64;
  const int lr = lane & 15, quad = lane >> 4;

  const int srow = wave * 32 + (lane >> 2);
  const int scol = (lane & 3) * 8;
  const unsigned short* ga = A + (size_t)(row0 + srow) * K + scol;
  const unsigned short* gb = Bt + (size_t)(col0 + srow) * K + scol;
  unsigned short* la0 = &As[wave * 32][0];
  unsigned short* la1 = &As[wave * 32 + 16][0];
  unsigned short* lb0 = &Bs[wave * 32][0];
  unsigned short* lb1 = &Bs[wave * 32 + 16][0];
  const size_t rstep = (size_t)16 * K;

  f32x4 acc[4][4];
#pragma unroll
  for (int a = 0; a < 4; a++)
#pragma unroll
    for (int b = 0; b < 4; b++) {
      acc[a][b][0] = 0.f; acc[a][b][1] = 0.f;
      acc[a][b][2] = 0.f; acc[a][b][3] = 0.f;
    }

  for (int k0 = 0; k0 < K; k0 += 32) {
    __syncthreads();
    async16(ga, la0);
    async16(ga + rstep, la1);
    async16(gb, lb0);
    async16(gb + rstep, lb1);
    ga += 32;
    gb += 32;
    __syncthreads();
    short8 af[4], bf[4];
#pragma unroll
    for (int mi = 0; mi < 4; mi++)
      af[mi] = *(const short8*)&As[wm + mi * 16 + lr][quad * 8];
#pragma unroll
    for (int ni = 0; ni < 4; ni++)
      bf[ni] = *(const short8*)&Bs[wn + ni * 16 + lr][quad * 8];
#pragma unroll
    for (int mi = 0; mi < 4; mi++)
#pragma unroll
      for (int ni = 0; ni < 4; ni++)
        acc[mi][ni] = __builtin_amdgcn_mfma_f32_16x16x32_bf16(
            af[mi], bf[ni], acc[mi][ni], 0, 0, 0);
  }

  const int cbase = col0 + wn + lr;
  float bv[4];
  if constexpr (BIAS) {
#pragma unroll
    for (int ni = 0; ni < 4; ni++) bv[ni] = bias[cbase + ni * 16];
  }
#pragma unroll
  for (int mi = 0; mi < 4; mi++) {
    const int r0 = row0 + wm + mi * 16 + quad * 4;
#pragma unroll
    for (int ni = 0; ni < 4; ni++) {
      const int cc = cbase + ni * 16;
#pragma unroll
      for (int e = 0; e < 4; e++) {
        float v = acc[mi][ni][e];
        if constexpr (BIAS) v += bv[ni];
        if constexpr (ACT == ACT_RELU) v = fmaxf(v, 0.f);
        else if constexpr (ACT == ACT_SIG) v = 1.f / (1.f + expf(-v));
        else if constexpr (ACT == ACT_TANH) v = tanhf(v);
        if constexpr (OUT16)
          ((unsigned short*)Cv)[(size_t)(r0 + e) * ldc + cc] = f2bf(v);
        else
          ((float*)Cv)[(size_t)(r0 + e) * ldc + cc] = v;
      }
    }
  }
}

// ---------------- fused flash attention (bf16 MFMA) ----------------
// grid (i-tile 8, head 16, batch 4), 256 thr = 4 waves; wave w owns rows
// w*16..w*16+15 of the 64-row i-tile. MFMA layouts identical to mgemm
// (validated R2): A[m=lane&15][k=quad*8+j], C col=lane&15 row=quad*4+e.
#define FA_PAD 72
__global__ __launch_bounds__(256) void fused_attn(
    const unsigned short* __restrict__ heads,  // [4096][3072] bf16
    const unsigned short* __restrict__ rk,     // [1024][1024] bf16
    const float* __restrict__ rwb, const float* __restrict__ rrb,
    unsigned short* __restrict__ attnb,        // [2048][1024] bf16
    float* __restrict__ ent) {
  const int it0 = blockIdx.x, n = blockIdx.y, b = blockIdx.z;
  const int i0 = it0 * 64;
  const int tid = threadIdx.x;
  const int wave = tid >> 6, lane = tid & 63;
  const int lr = lane & 15, quad = lane >> 4;
  const int wm = wave * 16;

  __shared__ __align__(16) unsigned short Qw[64][FA_PAD];
  __shared__ __align__(16) unsigned short Qr[64][FA_PAD];
  __shared__ __align__(16) unsigned short Ks[64][FA_PAD];
  __shared__ __align__(16) unsigned short Rk[64][FA_PAD];
  __shared__ __align__(16) unsigned short Pt[64][FA_PAD];
  __shared__ __align__(16) unsigned short Vt[64][FA_PAD];
  __shared__ __align__(16) unsigned short BDr[2][64][FA_PAD];
  __shared__ float entred[16];

  // ---- stage Q with both biases pre-added ----
#pragma unroll
  for (int s = tid; s < 512; s += 256) {
    const int row = s >> 3, vc = (s & 7) * 8;
    short8 v = *(const short8*)(heads +
        ((size_t)(MLEN + i0 + row) * BSZ + b) * HC + n * DH + vc);
    short8 qw, qr;
#pragma unroll
    for (int e = 0; e < 8; e++) {
      float f = bf2f((unsigned short)v[e]);
      qw[e] = (short)f2bf(f + rwb[n * DH + vc + e]);
      qr[e] = (short)f2bf(f + rrb[n * DH + vc + e]);
    }
    *(short8*)&Qw[row][vc] = qw;
    *(short8*)&Qr[row][vc] = qr;
    // pre-loop rk tile (7 - it0) into Rk
    short8 rv = *(const short8*)(rk +
        (size_t)((7 - it0) * 64 + row) * DM + n * DH + vc);
    *(short8*)&Rk[row][vc] = rv;
  }
  __syncthreads();
  // pre-loop BD tile -> ring slot 0 (wave-private rows)
  {
    f32x4 bd[4];
#pragma unroll
    for (int ni = 0; ni < 4; ni++) {
      bd[ni][0] = 0.f; bd[ni][1] = 0.f; bd[ni][2] = 0.f; bd[ni][3] = 0.f;
    }
#pragma unroll
    for (int ks = 0; ks < 2; ks++) {
      short8 aq = *(const short8*)&Qr[wm + lr][ks * 32 + quad * 8];
#pragma unroll
      for (int ni = 0; ni < 4; ni++) {
        short8 br = *(const short8*)&Rk[ni * 16 + lr][ks * 32 + quad * 8];
        bd[ni] = __builtin_amdgcn_mfma_f32_16x16x32_bf16(aq, br, bd[ni], 0, 0, 0);
      }
    }
#pragma unroll
    for (int ni = 0; ni < 4; ni++)
#pragma unroll
      for (int e = 0; e < 4; e++)
        BDr[0][wm + quad * 4 + e][ni * 16 + lr] = f2bf(bd[ni][e]);
  }

  f32x4 O[4];
#pragma unroll
  for (int d = 0; d < 4; d++) {
    O[d][0] = 0.f; O[d][1] = 0.f; O[d][2] = 0.f; O[d][3] = 0.f;
  }
  float mrow[4] = {-INFINITY, -INFINITY, -INFINITY, -INFINITY};
  float lrow[4] = {0.f, 0.f, 0.f, 0.f};
  float erow[4] = {0.f, 0.f, 0.f, 0.f};

  const int nj = it0 + 9;
  for (int t = 0; t < nj; t++) {
    const int j0 = t * 64;
    const int rtile = 8 - it0 + t;     // hi rk tile this iteration
    const int hi = (t + 1) & 1, lo = t & 1;
    __syncthreads();  // prior iteration's reads of Ks/Vt/Rk/ring-hi done
    // ---- stage K, V^T, next rk tile ----
#pragma unroll
    for (int s = tid; s < 512; s += 256) {
      const int row = s >> 3, vc = (s & 7) * 8;
      const size_t gbase = ((size_t)(j0 + row) * BSZ + b) * HC + n * DH + vc;
      short8 kv = *(const short8*)(heads + gbase + DM);
      *(short8*)&Ks[row][vc] = kv;
      short8 vv = *(const short8*)(heads + gbase + 2 * DM);
#pragma unroll
      for (int e = 0; e < 8; e++) Vt[vc + e][row] = (unsigned short)vv[e];
      if (rtile < 16) {
        short8 rv = *(const short8*)(rk +
            (size_t)(rtile * 64 + row) * DM + n * DH + vc);
        *(short8*)&Rk[row][vc] = rv;
      }
    }
    __syncthreads();
    // ---- BD (new hi tile) + AC MFMA ----
    f32x4 ac[4], bd[4];
#pragma unroll
    for (int ni = 0; ni < 4; ni++) {
      ac[ni][0] = 0.f; ac[ni][1] = 0.f; ac[ni][2] = 0.f; ac[ni][3] = 0.f;
      bd[ni][0] = 0.f; bd[ni][1] = 0.f; bd[ni][2] = 0.f; bd[ni][3] = 0.f;
    }
#pragma unroll
    for (int ks = 0; ks < 2; ks++) {
      short8 aw = *(const short8*)&Qw[wm + lr][ks * 32 + quad * 8];
      short8 aq = *(const short8*)&Qr[wm + lr][ks * 32 + quad * 8];
#pragma unroll
      for (int ni = 0; ni < 4; ni++) {
        short8 bk = *(const short8*)&Ks[ni * 16 + lr][ks * 32 + quad * 8];
        ac[ni] = __builtin_amdgcn_mfma_f32_16x16x32_bf16(aw, bk, ac[ni], 0, 0, 0);
        short8 br = *(const short8*)&Rk[ni * 16 + lr][ks * 32 + quad * 8];
        bd[ni] = __builtin_amdgcn_mfma_f32_16x16x32_bf16(aq, br, bd[ni], 0, 0, 0);
      }
    }
    if (rtile < 16) {
#pragma unroll
      for (int ni = 0; ni < 4; ni++)
#pragma unroll
        for (int e = 0; e < 4; e++)
          BDr[hi][wm + quad * 4 + e][ni * 16 + lr] = f2bf(bd[ni][e]);
    }
    // ---- scores: AC + shifted BD, mask, scale ----
    float sc[4][4];
#pragma unroll
    for (int ni = 0; ni < 4; ni++) {
      const int jl = ni * 16 + lr;
#pragma unroll
      for (int e = 0; e < 4; e++) {
        const int il = wm + quad * 4 + e;
        const int jjrel = jl + 63 - il;  // in [0,126]
        const float bdv =
            bf2f(BDr[jjrel >= 64 ? hi : lo][il][jjrel & 63]);
        const bool masked = (j0 + jl) > (i0 + il + MLEN);
        sc[ni][e] = masked ? -INFINITY : (ac[ni][e] + bdv) * 0.125f;
      }
    }
    // ---- online softmax (row stats across the 16 col-lanes) ----
#pragma unroll
    for (int e = 0; e < 4; e++) {
      const int il = wm + quad * 4 + e;
      float tm = fmaxf(fmaxf(sc[0][e], sc[1][e]), fmaxf(sc[2][e], sc[3][e]));
#pragma unroll
      for (int msk = 1; msk < 16; msk <<= 1)
        tm = fmaxf(tm, __shfl_xor(tm, msk, 64));
      const float mo = mrow[e];
      const float mn = fmaxf(mo, tm);
      const float al = __expf(mo - mn);
      float psum = 0.f, pes = 0.f, ps[4];
#pragma unroll
      for (int ni = 0; ni < 4; ni++) {
        const float s_ = sc[ni][e];
        const float p = __expf(s_ - mn);
        ps[ni] = p;
        psum += p;
        pes += (p > 0.f) ? p * s_ : 0.f;
      }
#pragma unroll
      for (int msk = 1; msk < 16; msk <<= 1) {
        psum += __shfl_xor(psum, msk, 64);
        pes += __shfl_xor(pes, msk, 64);
      }
      lrow[e] = lrow[e] * al + psum;
      erow[e] = erow[e] * al + pes;
      mrow[e] = mn;
#pragma unroll
      for (int d = 0; d < 4; d++) O[d][e] *= al;
#pragma unroll
      for (int ni = 0; ni < 4; ni++)
        Pt[il][ni * 16 + lr] = f2bf(ps[ni]);
    }
    // ---- PV MFMA (Pt rows wave-private; Vt staged this iteration) ----
#pragma unroll
    for (int ks = 0; ks < 2; ks++) {
      short8 ap = *(const short8*)&Pt[wm + lr][ks * 32 + quad * 8];
#pragma unroll
      for (int d = 0; d < 4; d++) {
        short8 bv = *(const short8*)&Vt[d * 16 + lr][ks * 32 + quad * 8];
        O[d] = __builtin_amdgcn_mfma_f32_16x16x32_bf16(ap, bv, O[d], 0, 0, 0);
      }
    }
  }

  // ---- epilogue: normalize, store, entropy ----
#pragma unroll
  for (int e = 0; e < 4; e++) {
    const int il = wm + quad * 4 + e;
    const float invl = 1.f / lrow[e];
#pragma unroll
    for (int d = 0; d < 4; d++)
      attnb[((size_t)(i0 + il) * BSZ + b) * DM + n * DH + d * 16 + lr] =
          f2bf(O[d][e] * invl);
  }
  if (lr == 0) {
    float esum = 0.f;
#pragma unroll
    for (int e = 0; e < 4; e++)
      esum += mrow[e] + __logf(lrow[e]) - erow[e] / lrow[e];
    entred[wave * 4 + quad] = esum;
  }
  __syncthreads();
  if (tid == 0) {
    float tsum = 0.f;
#pragma unroll
    for (int k = 0; k < 16; k++) tsum += entred[k];
    atomicAdd(ent + n, tsum * (1.f / (QLEN * BSZ)));
  }
}

// ---------------- weight cast+transpose: dst[n][k] = bf16(src[k][n]) -------
__global__ __launch_bounds__(256) void castT(
    const float* __restrict__ src, int K, int N,
    unsigned short* __restrict__ dst, int dstStride, int colOff) {
  (void)K;
  __shared__ float T[64][65];
  const int tid = threadIdx.x;
  const int n0 = blockIdx.x * 64, k0 = blockIdx.y * 64;
  const int tx = tid & 15, ty = tid >> 4;
#pragma unroll
  for (int l = 0; l < 4; l++) {
    const int k = ty + l * 16;
    float4 v = *(const float4*)(src + (size_t)(k0 + k) * N + n0 + tx * 4);
    T[tx * 4 + 0][k] = v.x;
    T[tx * 4 + 1][k] = v.y;
    T[tx * 4 + 2][k] = v.z;
    T[tx * 4 + 3][k] = v.w;
  }
  __syncthreads();
#pragma unroll
  for (int l = 0; l < 4; l++) {
    const int n = ty + l * 16;
    ushort4 o = {f2bf(T[n][tx * 4 + 0]), f2bf(T[n][tx * 4 + 1]),
                 f2bf(T[n][tx * 4 + 2]), f2bf(T[n][tx * 4 + 3])};
    *(ushort4*)(dst + (size_t)(n0 + n) * dstStride + colOff + k0 + tx * 4) = o;
  }
}

// ---------------- fp32 -> bf16 row cast (cols = 1024, strided dst) ---------
__global__ __launch_bounds__(256) void castRows(
    const float* __restrict__ src, unsigned short* __restrict__ dst,
    int dstStride) {
  const size_t e0 = ((size_t)blockIdx.x * 256 + threadIdx.x) * 4;
  const size_t m = e0 >> 10, c = e0 & 1023;
  float4 v = *(const float4*)(src + e0);
  ushort4 o = {f2bf(v.x), f2bf(v.y), f2bf(v.z), f2bf(v.w)};
  *(ushort4*)(dst + m * dstStride + c) = o;
}

// ---------------- elementwise ----------------
__global__ __launch_bounds__(256) void ew_rx(
    const float* __restrict__ zr, const float* __restrict__ x,
    unsigned short* __restrict__ ayx) {
  const size_t e0 = ((size_t)blockIdx.x * 256 + threadIdx.x) * 4;
  const size_t m = e0 >> 10, c = e0 & 1023;
  float4 rr = *(const float4*)(zr + m * 2048 + 1024 + c);
  float4 xx = *(const float4*)(x + e0);
  ushort4 o = {f2bf(rr.x * xx.x), f2bf(rr.y * xx.y),
               f2bf(rr.z * xx.z), f2bf(rr.w * xx.w)};
  *(ushort4*)(ayx + m * 2048 + 1024 + c) = o;
}
__global__ __launch_bounds__(256) void ew_out(
    const float* __restrict__ zr, const float* __restrict__ x,
    const float* __restrict__ h, float* __restrict__ o) {
  const size_t e0 = ((size_t)blockIdx.x * 256 + threadIdx.x) * 4;
  const size_t m = e0 >> 10, c = e0 & 1023;
  float4 zz = *(const float4*)(zr + m * 2048 + c);
  float4 xx = *(const float4*)(x + e0);
  float4 hh = *(const float4*)(h + e0);
  float4 r;
  r.x = (1.f - zz.x) * xx.x + zz.x * hh.x;
  r.y = (1.f - zz.y) * xx.y + zz.y * hh.y;
  r.z = (1.f - zz.z) * xx.z + zz.z * hh.z;
  r.w = (1.f - zz.w) * xx.w + zz.w * hh.w;
  *(float4*)(o + e0) = r;
}

__global__ void fill_bias(const float* __restrict__ b, float* __restrict__ d) {
  const int i = blockIdx.x * 256 + threadIdx.x;
  if (i < 2048) d[i] = (i < 1024) ? b[i] : 0.f;
}
__global__ void zero16(float* p) {
  if (threadIdx.x < 16) p[threadIdx.x] = 0.f;
}

// ---------------------------------------------------------------------------
extern "C" void kernel_launch(void* const* d_in, const int* in_sizes, int n_in,
                              void* d_out, int out_size, void* d_ws,
                              size_t ws_size, hipStream_t stream) {
  (void)in_sizes; (void)n_in; (void)out_size; (void)ws_size;
  const float* w      = (const float*)d_in[0];
  const float* mems   = (const float*)d_in[1];
  const float* r      = (const float*)d_in[2];
  const float* rwb    = (const float*)d_in[3];
  const float* rrb    = (const float*)d_in[4];
  const float* ln_a_w = (const float*)d_in[6];
  const float* ln_a_b = (const float*)d_in[7];
  const float* W_qkv  = (const float*)d_in[8];
  const float* W_r    = (const float*)d_in[9];
  const float* W_o    = (const float*)d_in[10];
  const float* ln2_w  = (const float*)d_in[11];
  const float* ln2_b  = (const float*)d_in[12];
  const float* ff_W1  = (const float*)d_in[13];
  const float* ff_b1  = (const float*)d_in[14];
  const float* ff_W2  = (const float*)d_in[15];
  const float* ff_b2  = (const float*)d_in[16];
  const float* gm_Wr  = (const float*)d_in[17];
  const float* gm_Ur  = (const float*)d_in[18];
  const float* gm_Uz  = (const float*)d_in[19];
  const float* gm_Wg  = (const float*)d_in[20];
  const float* gm_Ug  = (const float*)d_in[21];
  const float* gm_Wz  = (const float*)d_in[22];
  const float* gm_bz  = (const float*)d_in[23];
  const float* gp_Wr  = (const float*)d_in[24];
  const float* gp_Ur  = (const float*)d_in[25];
  const float* gp_Uz  = (const float*)d_in[26];
  const float* gp_Wg  = (const float*)d_in[27];
  const float* gp_Ug  = (const float*)d_in[28];
  const float* gp_Wz  = (const float*)d_in[29];
  const float* gp_bz  = (const float*)d_in[30];

  float* out = (float*)d_out;
  float* ent = out + (size_t)NROWS * DM;

  // ---- workspace carve (bytes) ----
  char* base = (char*)d_ws;
  size_t o = 0;
  unsigned short* wt_qkv   = (unsigned short*)(base + o); o += (size_t)3072 * 1024 * 2;
  unsigned short* wt_r     = (unsigned short*)(base + o); o += (size_t)1024 * 1024 * 2;
  unsigned short* wt_o     = (unsigned short*)(base + o); o += (size_t)1024 * 1024 * 2;
  unsigned short* wt_gm_zr = (unsigned short*)(base + o); o += (size_t)2048 * 2048 * 2;
  unsigned short* wt_gm_g  = (unsigned short*)(base + o); o += (size_t)1024 * 2048 * 2;
  unsigned short* wt_gp_zr = (unsigned short*)(base + o); o += (size_t)2048 * 2048 * 2;
  unsigned short* wt_gp_g  = (unsigned short*)(base + o); o += (size_t)1024 * 2048 * 2;
  unsigned short* wt_ff1   = (unsigned short*)(base + o); o += (size_t)4096 * 1024 * 2;
  unsigned short* wt_ff2   = (unsigned short*)(base + o); o += (size_t)1024 * 4096 * 2;
  float* bias_gm = (float*)(base + o); o += 2048 * 4;
  float* bias_gp = (float*)(base + o); o += 2048 * 4;
  // heads region: bf16 heads [4096][3072]; overlaid with gate temps later
  char* hreg = base + o;  o += (size_t)HR * HC * 2 + (size_t)16 * 1024 * 1024;
  unsigned short* heads_bf = (unsigned short*)hreg;          // 25.2 MB
  unsigned short* Ayx = (unsigned short*)hreg;               // 8.39 MB
  float* zr   = (float*)(hreg + 8388608);                    // 16.8 MB
  float* hbuf = (float*)(hreg + 25165824);                   // 8.39 MB
  float* o1   = (float*)(hreg + 33554432);                   // 8.39 MB
  char* sreg = base + o;  o += (size_t)NROWS * DI * 2;       // 16.8 MB
  unsigned short* ffh_bf = (unsigned short*)sreg;
  unsigned short* attnb_bf = (unsigned short*)(base + o); o += (size_t)NROWS * DM * 2;
  char* misc = base + o;  o += 8388608;
  unsigned short* lncat_bf = (unsigned short*)misc;          // 8.39 MB
  unsigned short* r_bf = (unsigned short*)misc;              // 2 MB (after QKV)
  unsigned short* rk_bf = (unsigned short*)(misc + 4194304); // 2 MB
  unsigned short* lnb_bf = (unsigned short*)misc;            // 4.2 MB (phase 4)

  // ---- phase 0: weight cast/transpose + biases ----
  castT<<<dim3(48, 16), 256, 0, stream>>>(W_qkv, 1024, 3072, wt_qkv, 1024, 0);
  castT<<<dim3(16, 16), 256, 0, stream>>>(W_r, 1024, 1024, wt_r, 1024, 0);
  castT<<<dim3(16, 16), 256, 0, stream>>>(W_o, 1024, 1024, wt_o, 1024, 0);
  castT<<<dim3(16, 16), 256, 0, stream>>>(gm_Wz, 1024, 1024, wt_gm_zr, 2048, 0);
  castT<<<dim3(16, 16), 256, 0, stream>>>(gm_Uz, 1024, 1024, wt_gm_zr, 2048, 1024);
  castT<<<dim3(16, 16), 256, 0, stream>>>(gm_Wr, 1024, 1024, wt_gm_zr + (size_t)1024 * 2048, 2048, 0);
  castT<<<dim3(16, 16), 256, 0, stream>>>(gm_Ur, 1024, 1024, wt_gm_zr + (size_t)1024 * 2048, 2048, 1024);
  castT<<<dim3(16, 16), 256, 0, stream>>>(gm_Wg, 1024, 1024, wt_gm_g, 2048, 0);
  castT<<<dim3(16, 16), 256, 0, stream>>>(gm_Ug, 1024, 1024, wt_gm_g, 2048, 1024);
  castT<<<dim3(16, 16), 256, 0, stream>>>(gp_Wz, 1024, 1024, wt_gp_zr, 2048, 0);
  castT<<<dim3(16, 16), 256, 0, stream>>>(gp_Uz, 1024, 1024, wt_gp_zr, 2048, 1024);
  castT<<<dim3(16, 16), 256, 0, stream>>>(gp_Wr, 1024, 1024, wt_gp_zr + (size_t)1024 * 2048, 2048, 0);
  castT<<<dim3(16, 16), 256, 0, stream>>>(gp_Ur, 1024, 1024, wt_gp_zr + (size_t)1024 * 2048, 2048, 1024);
  castT<<<dim3(16, 16), 256, 0, stream>>>(gp_Wg, 1024, 1024, wt_gp_g, 2048, 0);
  castT<<<dim3(16, 16), 256, 0, stream>>>(gp_Ug, 1024, 1024, wt_gp_g, 2048, 1024);
  castT<<<dim3(64, 16), 256, 0, stream>>>(ff_W1, 1024, 4096, wt_ff1, 1024, 0);
  castT<<<dim3(16, 64), 256, 0, stream>>>(ff_W2, 4096, 1024, wt_ff2, 4096, 0);
  fill_bias<<<8, 256, 0, stream>>>(gm_bz, bias_gm);
  fill_bias<<<8, 256, 0, stream>>>(gp_bz, bias_gp);
  zero16<<<1, 64, 0, stream>>>(ent);

  // ---- phase 1: LN + QKV / r projections (bf16 outputs) ----
  ln_kernel<true><<<HR, 256, 0, stream>>>(mems, w, ln_a_w, ln_a_b, lncat_bf);
  mgemm<ACT_NONE, false, true><<<dim3(24, 32), 256, 0, stream>>>(
      lncat_bf, wt_qkv, heads_bf, nullptr, HR, HC, 1024, HC);
  castRows<<<1024, 256, 0, stream>>>(r, r_bf, 1024);
  mgemm<ACT_NONE, false, true><<<dim3(8, 8), 256, 0, stream>>>(
      r_bf, wt_r, rk_bf, nullptr, 1024, 1024, 1024, 1024);

  // ---- phase 2: fused attention ----
  fused_attn<<<dim3(8, NH, BSZ), 256, 0, stream>>>(heads_bf, rk_bf, rwb, rrb,
                                                   attnb_bf, ent);

  // ---- phase 3: W_o + gm GRU gate (heads now dead; overlays live) ----
  mgemm<ACT_RELU, false, true><<<dim3(8, 16), 256, 0, stream>>>(
      attnb_bf, wt_o, Ayx, nullptr, NROWS, 1024, 1024, 2048);
  castRows<<<2048, 256, 0, stream>>>(w, Ayx + 1024, 2048);
  mgemm<ACT_SIG, true, false><<<dim3(16, 16), 256, 0, stream>>>(
      Ayx, wt_gm_zr, zr, bias_gm, NROWS, 2048, 2048, 2048);
  ew_rx<<<2048, 256, 0, stream>>>(zr, w, Ayx);
  mgemm<ACT_TANH, false, false><<<dim3(8, 16), 256, 0, stream>>>(
      Ayx, wt_gm_g, hbuf, nullptr, NROWS, 1024, 2048, 1024);
  ew_out<<<2048, 256, 0, stream>>>(zr, w, hbuf, o1);

  // ---- phase 4: FF ----
  ln_kernel<false><<<NROWS, 256, 0, stream>>>(o1, nullptr, ln2_w, ln2_b,
                                              lnb_bf);
  mgemm<ACT_RELU, true, true><<<dim3(32, 16), 256, 0, stream>>>(
      lnb_bf, wt_ff1, ffh_bf, ff_b1, NROWS, DI, 1024, DI);
  mgemm<ACT_RELU, true, true><<<dim3(8, 16), 256, 0, stream>>>(
      ffh_bf, wt_ff2, Ayx, ff_b2, NROWS, 1024, DI, 2048);
  castRows<<<2048, 256, 0, stream>>>(o1, Ayx + 1024, 2048);

  // ---- phase 5: gp GRU gate ----
  mgemm<ACT_SIG, true, false><<<dim3(16, 16), 256, 0, stream>>>(
      Ayx, wt_gp_zr, zr, bias_gp, NROWS, 2048, 2048, 2048);
  ew_rx<<<2048, 256, 0, stream>>>(zr, o1, Ayx);
  mgemm<ACT_TANH, false, false><<<dim3(8, 16), 256, 0, stream>>>(
      Ayx, wt_gp_g, hbuf, nullptr, NROWS, 1024, 2048, 1024);
  ew_out<<<2048, 256, 0, stream>>>(zr, o1, hbuf, out);
}

// Round 4
// 670.033 us; speedup vs baseline: 6.0747x; 1.1460x over previous
//
#include <hip/hip_runtime.h>
#include <math.h>

// ---------------------------------------------------------------------------
// Transformer-XL RelPartialLearnableDecoderLayer.
// Round 4: per-head dense Q/K/Vt/rk layouts written by GEMM epilogues
// (conflict-free fused attention staging), BM=64 GEMM variant for N=1024
// shapes (full-device grids), batched weight transpose, fused epilogues.
// rel_shift closed form: BD[i,j] = BD_raw[i, j+511-i]; mask j > i+512.
// ---------------------------------------------------------------------------

#define QLEN 512
#define MLEN 512
#define KLEN 1024
#define BSZ  4
#define DM   1024
#define DI   4096
#define NH   16
#define DH   64
#define HC   (3*DM)
#define HR   (KLEN*BSZ)   // 4096
#define NROWS (QLEN*BSZ)  // 2048

enum { ACT_NONE = 0, ACT_RELU = 1, ACT_SIG = 2, ACT_TANH = 3 };
enum { MODE_NORM = 0, MODE_QKV = 1, MODE_RK = 2 };

using short8 = __attribute__((ext_vector_type(8))) short;
using f32x4  = __attribute__((ext_vector_type(4))) float;

__device__ __forceinline__ unsigned short f2bf(float f) {
  union { float f; unsigned u; } v;
  v.f = f;
  unsigned r = v.u + 0x7FFFu + ((v.u >> 16) & 1u);  // RNE
  return (unsigned short)(r >> 16);
}
__device__ __forceinline__ float bf2f(unsigned short u) {
  union { unsigned u; float f; } v;
  v.u = ((unsigned)u) << 16;
  return v.f;
}

__device__ __forceinline__ void async16(const void* g, void* l) {
  __builtin_amdgcn_global_load_lds(
      (const __attribute__((address_space(1))) void*)g,
      (__attribute__((address_space(3))) void*)l, 16, 0, 0);
}

__device__ __forceinline__ float waveSum(float v) {
#pragma unroll
  for (int o = 32; o; o >>= 1) v += __shfl_down(v, o, 64);
  return v;
}

// ---------------- LayerNorm -> bf16 ----------------
template <bool CONCAT>
__global__ __launch_bounds__(256) void ln_kernel(
    const float* __restrict__ a, const float* __restrict__ a2,
    const float* __restrict__ wt, const float* __restrict__ bs,
    unsigned short* __restrict__ dst) {
  const int row = blockIdx.x;
  const int tid = threadIdx.x;
  const float* srow;
  if (CONCAT)
    srow = (row < MLEN * BSZ) ? a + (size_t)row * DM
                              : a2 + (size_t)(row - MLEN * BSZ) * DM;
  else
    srow = a + (size_t)row * DM;
  float4 x = *(const float4*)(srow + tid * 4);
  float s = x.x + x.y + x.z + x.w;
  float q = x.x * x.x + x.y * x.y + x.z * x.z + x.w * x.w;
  __shared__ float2 red[4];
  float2 p;
  p.x = waveSum(s);
  p.y = waveSum(q);
  if ((tid & 63) == 0) red[tid >> 6] = p;
  __syncthreads();
  float S = red[0].x + red[1].x + red[2].x + red[3].x;
  float Q = red[0].y + red[1].y + red[2].y + red[3].y;
  const float inv = 1.0f / DM;
  float mu = S * inv;
  float var = Q * inv - mu * mu;
  float rs = rsqrtf(var + 1e-5f);
  float4 w4 = *(const float4*)(wt + tid * 4);
  float4 b4 = *(const float4*)(bs + tid * 4);
  ushort4 o = {f2bf((x.x - mu) * rs * w4.x + b4.x),
               f2bf((x.y - mu) * rs * w4.y + b4.y),
               f2bf((x.z - mu) * rs * w4.z + b4.z),
               f2bf((x.w - mu) * rs * w4.w + b4.w)};
  *(ushort4*)(dst + (size_t)row * DM + tid * 4) = o;
}

// ---------------- bf16 MFMA GEMM:  C = act(A @ Bt^T [+bias]) ---------------
// BM=128: 128x128 tile, 4 waves 2x2 of 64x64 (m97 structure, validated).
// BM=64: 64x128 tile, 4 waves each 16x128 (for N=1024 / occupancy-bound).
// MODE_QKV: scatter C (heads) into per-head dense Q_g/K_g/V_gT buffers.
// MODE_RK:  scatter C (rk)    into per-head dense rk_g.
// xsrc != nullptr: epilogue also writes bf16(xsrc[m][c]) to C col 1024+c.
template <int BM, int ACT, bool BIAS, int MODE, bool OUT16>
__global__ __launch_bounds__(256) void mgemm(
    const unsigned short* __restrict__ A, const unsigned short* __restrict__ Bt,
    void* __restrict__ Cv, const float* __restrict__ bias,
    const float* __restrict__ xsrc,
    unsigned short* __restrict__ g0, unsigned short* __restrict__ g1,
    unsigned short* __restrict__ g2,
    int M, int N, int K, int ldc) {
  (void)M; (void)N;
  constexpr int TM = (BM == 128) ? 4 : 1;
  constexpr int TN = (BM == 128) ? 4 : 8;
  __shared__ __align__(16) unsigned short As[BM][32];
  __shared__ __align__(16) unsigned short Bs[128][32];
  const int tid = threadIdx.x;
  const int wave = tid >> 6, lane = tid & 63;
  const int row0 = blockIdx.y * BM, col0 = blockIdx.x * 128;
  const int wm = (BM == 128) ? (wave >> 1) * 64 : wave * 16;
  const int wn = (BM == 128) ? (wave & 1) * 64 : 0;
  const int lr = lane & 15, quad = lane >> 4;

  const int sr = lane >> 2, sc = (lane & 3) * 8;
  const size_t rstep = (size_t)16 * K;
  const unsigned short* ga;
  const unsigned short* gb = Bt + (size_t)(col0 + wave * 32 + sr) * K + sc;
  unsigned short* lb0 = &Bs[wave * 32][0];
  unsigned short* lb1 = &Bs[wave * 32 + 16][0];
  unsigned short* la0;
  unsigned short* la1 = nullptr;
  if constexpr (BM == 128) {
    ga = A + (size_t)(row0 + wave * 32 + sr) * K + sc;
    la0 = &As[wave * 32][0];
    la1 = &As[wave * 32 + 16][0];
  } else {
    ga = A + (size_t)(row0 + wave * 16 + sr) * K + sc;
    la0 = &As[wave * 16][0];
  }

  f32x4 acc[TM][TN];
#pragma unroll
  for (int a = 0; a < TM; a++)
#pragma unroll
    for (int b = 0; b < TN; b++) {
      acc[a][b][0] = 0.f; acc[a][b][1] = 0.f;
      acc[a][b][2] = 0.f; acc[a][b][3] = 0.f;
    }

  for (int k0 = 0; k0 < K; k0 += 32) {
    __syncthreads();
    async16(ga, la0);
    if constexpr (BM == 128) async16(ga + rstep, la1);
    async16(gb, lb0);
    async16(gb + rstep, lb1);
    ga += 32;
    gb += 32;
    __syncthreads();
    short8 af[TM], bf[TN];
#pragma unroll
    for (int mi = 0; mi < TM; mi++)
      af[mi] = *(const short8*)&As[wm + mi * 16 + lr][quad * 8];
#pragma unroll
    for (int ni = 0; ni < TN; ni++)
      bf[ni] = *(const short8*)&Bs[wn + ni * 16 + lr][quad * 8];
#pragma unroll
    for (int mi = 0; mi < TM; mi++)
#pragma unroll
      for (int ni = 0; ni < TN; ni++)
        acc[mi][ni] = __builtin_amdgcn_mfma_f32_16x16x32_bf16(
            af[mi], bf[ni], acc[mi][ni], 0, 0, 0);
  }

  const int cbase = col0 + wn + lr;
  float bv[TN];
  if constexpr (BIAS) {
#pragma unroll
    for (int ni = 0; ni < TN; ni++) bv[ni] = bias[cbase + ni * 16];
  }
  const int region = (MODE == MODE_QKV) ? (col0 >> 10) : 0;  // uniform
#pragma unroll
  for (int mi = 0; mi < TM; mi++) {
    const int r0 = row0 + wm + mi * 16 + quad * 4;
#pragma unroll
    for (int ni = 0; ni < TN; ni++) {
      const int cc = cbase + ni * 16;
#pragma unroll
      for (int e = 0; e < 4; e++) {
        float v = acc[mi][ni][e];
        if constexpr (BIAS) v += bv[ni];
        if constexpr (ACT == ACT_RELU) v = fmaxf(v, 0.f);
        else if constexpr (ACT == ACT_SIG) v = 1.f / (1.f + expf(-v));
        else if constexpr (ACT == ACT_TANH) v = tanhf(v);
        if constexpr (MODE == MODE_QKV) {
          const int rr = r0 + e;
          const int pos = rr >> 2, bb = rr & 3;
          const int cl = cc & 1023, hn = cl >> 6, d = cl & 63;
          const unsigned short hv = f2bf(v);
          if (region == 0) {
            if (pos >= MLEN)
              g0[(((size_t)(bb * NH + hn) * QLEN + (pos - MLEN)) << 6) + d] = hv;
          } else if (region == 1) {
            g1[(((size_t)(bb * NH + hn) * KLEN + pos) << 6) + d] = hv;
          } else {
            g2[(((size_t)(bb * NH + hn) * DH + d) << 10) + pos] = hv;
          }
        } else if constexpr (MODE == MODE_RK) {
          const int hn = cc >> 6, d = cc & 63;
          g0[(((size_t)hn * KLEN + (r0 + e)) << 6) + d] = f2bf(v);
        } else {
          if constexpr (OUT16)
            ((unsigned short*)Cv)[(size_t)(r0 + e) * ldc + cc] = f2bf(v);
          else
            ((float*)Cv)[(size_t)(r0 + e) * ldc + cc] = v;
        }
      }
      if (xsrc) {
#pragma unroll
        for (int e = 0; e < 4; e++)
          ((unsigned short*)Cv)[(size_t)(r0 + e) * ldc + 1024 + cc] =
              f2bf(xsrc[(size_t)(r0 + e) * 1024 + cc]);
      }
    }
  }
}

// ---------------- fused flash attention (bf16 MFMA, dense layouts) ---------
#define FA_PAD 72
#define PT_PAD 76
__global__ __launch_bounds__(256) void fused_attn(
    const unsigned short* __restrict__ Q_g,   // [b][n][512][64]
    const unsigned short* __restrict__ K_g,   // [b][n][1024][64]
    const unsigned short* __restrict__ V_gT,  // [b][n][64][1024]
    const unsigned short* __restrict__ rk_g,  // [n][1024][64]
    const float* __restrict__ rwb, const float* __restrict__ rrb,
    unsigned short* __restrict__ attnb,       // [2048][1024] bf16
    float* __restrict__ ent) {
  const int it0 = blockIdx.x, n = blockIdx.y, b = blockIdx.z;
  const int i0 = it0 * 64;
  const int tid = threadIdx.x;
  const int wave = tid >> 6, lane = tid & 63;
  const int lr = lane & 15, quad = lane >> 4;
  const int wm = wave * 16;

  __shared__ __align__(16) unsigned short Qw[64][FA_PAD];
  __shared__ __align__(16) unsigned short Qr[64][FA_PAD];
  __shared__ __align__(16) unsigned short Ks[64][FA_PAD];
  __shared__ __align__(16) unsigned short Rk[64][FA_PAD];
  __shared__ __align__(16) unsigned short Vt[64][FA_PAD];
  __shared__ __align__(16) unsigned short Pt[64][PT_PAD];
  __shared__ __align__(16) unsigned short BDr[2][64][PT_PAD];
  __shared__ float entred[16];

  const unsigned short* Qb = Q_g + (((size_t)(b * NH + n) * QLEN + i0) << 6);
  const unsigned short* Kb = K_g + (((size_t)(b * NH + n) * KLEN) << 6);
  const unsigned short* Vb = V_gT + (((size_t)(b * NH + n) * DH) << 10);
  const unsigned short* Rb = rk_g + (((size_t)n * KLEN) << 6);

  // ---- stage Q with both biases pre-added + pre-loop rk tile ----
#pragma unroll
  for (int s = tid; s < 512; s += 256) {
    const int row = s >> 3, vc = (s & 7) * 8;
    short8 v = *(const short8*)(Qb + row * 64 + vc);
    short8 qw, qr;
#pragma unroll
    for (int e = 0; e < 8; e++) {
      float f = bf2f((unsigned short)v[e]);
      qw[e] = (short)f2bf(f + rwb[n * DH + vc + e]);
      qr[e] = (short)f2bf(f + rrb[n * DH + vc + e]);
    }
    *(short8*)&Qw[row][vc] = qw;
    *(short8*)&Qr[row][vc] = qr;
    short8 rv = *(const short8*)(Rb + ((7 - it0) * 64 + row) * 64 + vc);
    *(short8*)&Rk[row][vc] = rv;
  }
  __syncthreads();
  // pre-loop BD tile -> ring slot 0 (wave-private rows)
  {
    f32x4 bd[4];
#pragma unroll
    for (int ni = 0; ni < 4; ni++) {
      bd[ni][0] = 0.f; bd[ni][1] = 0.f; bd[ni][2] = 0.f; bd[ni][3] = 0.f;
    }
#pragma unroll
    for (int ks = 0; ks < 2; ks++) {
      short8 aq = *(const short8*)&Qr[wm + lr][ks * 32 + quad * 8];
#pragma unroll
      for (int ni = 0; ni < 4; ni++) {
        short8 br = *(const short8*)&Rk[ni * 16 + lr][ks * 32 + quad * 8];
        bd[ni] = __builtin_amdgcn_mfma_f32_16x16x32_bf16(aq, br, bd[ni], 0, 0, 0);
      }
    }
#pragma unroll
    for (int ni = 0; ni < 4; ni++)
#pragma unroll
      for (int e = 0; e < 4; e++)
        BDr[0][wm + quad * 4 + e][ni * 16 + lr] = f2bf(bd[ni][e]);
  }

  f32x4 O[4];
#pragma unroll
  for (int d = 0; d < 4; d++) {
    O[d][0] = 0.f; O[d][1] = 0.f; O[d][2] = 0.f; O[d][3] = 0.f;
  }
  float mrow[4] = {-INFINITY, -INFINITY, -INFINITY, -INFINITY};
  float lrow[4] = {0.f, 0.f, 0.f, 0.f};
  float erow[4] = {0.f, 0.f, 0.f, 0.f};

  const int nj = it0 + 9;
  for (int t = 0; t < nj; t++) {
    const int j0 = t * 64;
    const int rtile = 8 - it0 + t;
    const int hi = (t + 1) & 1, lo = t & 1;
    __syncthreads();
    // ---- stage K, V^T, next rk tile (all dense short8) ----
#pragma unroll
    for (int s = tid; s < 512; s += 256) {
      const int row = s >> 3, vc = (s & 7) * 8;
      *(short8*)&Ks[row][vc] = *(const short8*)(Kb + (j0 + row) * 64 + vc);
      *(short8*)&Vt[row][vc] = *(const short8*)(Vb + row * 1024 + j0 + vc);
      if (rtile < 16)
        *(short8*)&Rk[row][vc] =
            *(const short8*)(Rb + (rtile * 64 + row) * 64 + vc);
    }
    __syncthreads();
    // ---- BD (new hi tile) + AC MFMA ----
    f32x4 ac[4], bd[4];
#pragma unroll
    for (int ni = 0; ni < 4; ni++) {
      ac[ni][0] = 0.f; ac[ni][1] = 0.f; ac[ni][2] = 0.f; ac[ni][3] = 0.f;
      bd[ni][0] = 0.f; bd[ni][1] = 0.f; bd[ni][2] = 0.f; bd[ni][3] = 0.f;
    }
#pragma unroll
    for (int ks = 0; ks < 2; ks++) {
      short8 aw = *(const short8*)&Qw[wm + lr][ks * 32 + quad * 8];
      short8 aq = *(const short8*)&Qr[wm + lr][ks * 32 + quad * 8];
#pragma unroll
      for (int ni = 0; ni < 4; ni++) {
        short8 bk = *(const short8*)&Ks[ni * 16 + lr][ks * 32 + quad * 8];
        ac[ni] = __builtin_amdgcn_mfma_f32_16x16x32_bf16(aw, bk, ac[ni], 0, 0, 0);
        short8 br = *(const short8*)&Rk[ni * 16 + lr][ks * 32 + quad * 8];
        bd[ni] = __builtin_amdgcn_mfma_f32_16x16x32_bf16(aq, br, bd[ni], 0, 0, 0);
      }
    }
    if (rtile < 16) {
#pragma unroll
      for (int ni = 0; ni < 4; ni++)
#pragma unroll
        for (int e = 0; e < 4; e++)
          BDr[hi][wm + quad * 4 + e][ni * 16 + lr] = f2bf(bd[ni][e]);
    }
    // ---- scores: AC + shifted BD, mask, scale ----
    float sc[4][4];
#pragma unroll
    for (int ni = 0; ni < 4; ni++) {
      const int jl = ni * 16 + lr;
#pragma unroll
      for (int e = 0; e < 4; e++) {
        const int il = wm + quad * 4 + e;
        const int jjrel = jl + 63 - il;  // in [0,126]
        const float bdv =
            bf2f(BDr[jjrel >= 64 ? hi : lo][il][jjrel & 63]);
        const bool masked = (j0 + jl) > (i0 + il + MLEN);
        sc[ni][e] = masked ? -INFINITY : (ac[ni][e] + bdv) * 0.125f;
      }
    }
    // ---- online softmax (row stats across the 16 col-lanes) ----
#pragma unroll
    for (int e = 0; e < 4; e++) {
      const int il = wm + quad * 4 + e;
      float tm = fmaxf(fmaxf(sc[0][e], sc[1][e]), fmaxf(sc[2][e], sc[3][e]));
#pragma unroll
      for (int msk = 1; msk < 16; msk <<= 1)
        tm = fmaxf(tm, __shfl_xor(tm, msk, 64));
      const float mo = mrow[e];
      const float mn = fmaxf(mo, tm);
      const float al = __expf(mo - mn);
      float psum = 0.f, pes = 0.f, ps[4];
#pragma unroll
      for (int ni = 0; ni < 4; ni++) {
        const float s_ = sc[ni][e];
        const float p = __expf(s_ - mn);
        ps[ni] = p;
        psum += p;
        pes += (p > 0.f) ? p * s_ : 0.f;
      }
#pragma unroll
      for (int msk = 1; msk < 16; msk <<= 1) {
        psum += __shfl_xor(psum, msk, 64);
        pes += __shfl_xor(pes, msk, 64);
      }
      lrow[e] = lrow[e] * al + psum;
      erow[e] = erow[e] * al + pes;
      mrow[e] = mn;
#pragma unroll
      for (int d = 0; d < 4; d++) O[d][e] *= al;
#pragma unroll
      for (int ni = 0; ni < 4; ni++)
        Pt[il][ni * 16 + lr] = f2bf(ps[ni]);
    }
    // ---- PV MFMA ----
#pragma unroll
    for (int ks = 0; ks < 2; ks++) {
      short8 ap = *(const short8*)&Pt[wm + lr][ks * 32 + quad * 8];
#pragma unroll
      for (int d = 0; d < 4; d++) {
        short8 bv = *(const short8*)&Vt[d * 16 + lr][ks * 32 + quad * 8];
        O[d] = __builtin_amdgcn_mfma_f32_16x16x32_bf16(ap, bv, O[d], 0, 0, 0);
      }
    }
  }

  // ---- epilogue: normalize, store, entropy ----
#pragma unroll
  for (int e = 0; e < 4; e++) {
    const int il = wm + quad * 4 + e;
    const float invl = 1.f / lrow[e];
#pragma unroll
    for (int d = 0; d < 4; d++)
      attnb[((size_t)(i0 + il) * BSZ + b) * DM + n * DH + d * 16 + lr] =
          f2bf(O[d][e] * invl);
  }
  if (lr == 0) {
    float esum = 0.f;
#pragma unroll
    for (int e = 0; e < 4; e++)
      esum += mrow[e] + __logf(lrow[e]) - erow[e] / lrow[e];
    entred[wave * 4 + quad] = esum;
  }
  __syncthreads();
  if (tid == 0) {
    float tsum = 0.f;
#pragma unroll
    for (int k = 0; k < 16; k++) tsum += entred[k];
    atomicAdd(ent + n, tsum * (1.f / (QLEN * BSZ)));
  }
}

// ---------------- batched weight cast+transpose ----------------
#define MAXD 18
struct TDesc {
  const float* src;
  unsigned short* dst;
  int N, dstStride, colOff, tilesX, tileBase;
};
struct TDescs { TDesc d[MAXD]; int n; };

__global__ __launch_bounds__(256) void castT_batch(TDescs ds) {
  const int bid = blockIdx.x;
  int di = 0;
  while (di + 1 < ds.n && ds.d[di + 1].tileBase <= bid) di++;
  const TDesc t = ds.d[di];
  const int lt = bid - t.tileBase;
  const int n0 = (lt % t.tilesX) * 64, k0 = (lt / t.tilesX) * 64;
  __shared__ float T[64][65];
  const int tid = threadIdx.x;
  const int tx = tid & 15, ty = tid >> 4;
#pragma unroll
  for (int l = 0; l < 4; l++) {
    const int k = ty + l * 16;
    float4 v = *(const float4*)(t.src + (size_t)(k0 + k) * t.N + n0 + tx * 4);
    T[tx * 4 + 0][k] = v.x;
    T[tx * 4 + 1][k] = v.y;
    T[tx * 4 + 2][k] = v.z;
    T[tx * 4 + 3][k] = v.w;
  }
  __syncthreads();
#pragma unroll
  for (int l = 0; l < 4; l++) {
    const int n = ty + l * 16;
    ushort4 o = {f2bf(T[n][tx * 4 + 0]), f2bf(T[n][tx * 4 + 1]),
                 f2bf(T[n][tx * 4 + 2]), f2bf(T[n][tx * 4 + 3])};
    *(ushort4*)(t.dst + (size_t)(n0 + n) * t.dstStride + t.colOff + k0 +
                tx * 4) = o;
  }
}

// ---------------- fp32 -> bf16 row cast ----------------
__global__ __launch_bounds__(256) void castRows(
    const float* __restrict__ src, unsigned short* __restrict__ dst,
    int dstStride) {
  const size_t e0 = ((size_t)blockIdx.x * 256 + threadIdx.x) * 4;
  const size_t m = e0 >> 10, c = e0 & 1023;
  float4 v = *(const float4*)(src + e0);
  ushort4 o = {f2bf(v.x), f2bf(v.y), f2bf(v.z), f2bf(v.w)};
  *(ushort4*)(dst + m * dstStride + c) = o;
}

// ---------------- elementwise ----------------
__global__ __launch_bounds__(256) void ew_rx(
    const float* __restrict__ zr, const float* __restrict__ x,
    unsigned short* __restrict__ ayx) {
  const size_t e0 = ((size_t)blockIdx.x * 256 + threadIdx.x) * 4;
  const size_t m = e0 >> 10, c = e0 & 1023;
  float4 rr = *(const float4*)(zr + m * 2048 + 1024 + c);
  float4 xx = *(const float4*)(x + e0);
  ushort4 o = {f2bf(rr.x * xx.x), f2bf(rr.y * xx.y),
               f2bf(rr.z * xx.z), f2bf(rr.w * xx.w)};
  *(ushort4*)(ayx + m * 2048 + 1024 + c) = o;
}
__global__ __launch_bounds__(256) void ew_out(
    const float* __restrict__ zr, const float* __restrict__ x,
    const float* __restrict__ h, float* __restrict__ o) {
  const size_t e0 = ((size_t)blockIdx.x * 256 + threadIdx.x) * 4;
  const size_t m = e0 >> 10, c = e0 & 1023;
  float4 zz = *(const float4*)(zr + m * 2048 + c);
  float4 xx = *(const float4*)(x + e0);
  float4 hh = *(const float4*)(h + e0);
  float4 r;
  r.x = (1.f - zz.x) * xx.x + zz.x * hh.x;
  r.y = (1.f - zz.y) * xx.y + zz.y * hh.y;
  r.z = (1.f - zz.z) * xx.z + zz.z * hh.z;
  r.w = (1.f - zz.w) * xx.w + zz.w * hh.w;
  *(float4*)(o + e0) = r;
}
// one row per block: o = (1-z)x + zh; write o fp32 and LN(o) bf16
__global__ __launch_bounds__(256) void ew_out_ln(
    const float* __restrict__ zr, const float* __restrict__ x,
    const float* __restrict__ h, const float* __restrict__ lw,
    const float* __restrict__ lb, float* __restrict__ ofp,
    unsigned short* __restrict__ obf) {
  const int m = blockIdx.x;
  const int tid = threadIdx.x;
  const int c = tid * 4;
  float4 zz = *(const float4*)(zr + (size_t)m * 2048 + c);
  float4 xx = *(const float4*)(x + (size_t)m * 1024 + c);
  float4 hh = *(const float4*)(h + (size_t)m * 1024 + c);
  float ov[4];
  ov[0] = (1.f - zz.x) * xx.x + zz.x * hh.x;
  ov[1] = (1.f - zz.y) * xx.y + zz.y * hh.y;
  ov[2] = (1.f - zz.z) * xx.z + zz.z * hh.z;
  ov[3] = (1.f - zz.w) * xx.w + zz.w * hh.w;
  *(float4*)(ofp + (size_t)m * 1024 + c) = *(float4*)ov;
  float s = ov[0] + ov[1] + ov[2] + ov[3];
  float q = ov[0] * ov[0] + ov[1] * ov[1] + ov[2] * ov[2] + ov[3] * ov[3];
  __shared__ float2 red[4];
  float2 p;
  p.x = waveSum(s);
  p.y = waveSum(q);
  if ((tid & 63) == 0) red[tid >> 6] = p;
  __syncthreads();
  float S = red[0].x + red[1].x + red[2].x + red[3].x;
  float Q = red[0].y + red[1].y + red[2].y + red[3].y;
  const float inv = 1.0f / DM;
  float mu = S * inv;
  float var = Q * inv - mu * mu;
  float rs = rsqrtf(var + 1e-5f);
  float4 w4 = *(const float4*)(lw + c);
  float4 b4 = *(const float4*)(lb + c);
  ushort4 o = {f2bf((ov[0] - mu) * rs * w4.x + b4.x),
               f2bf((ov[1] - mu) * rs * w4.y + b4.y),
               f2bf((ov[2] - mu) * rs * w4.z + b4.z),
               f2bf((ov[3] - mu) * rs * w4.w + b4.w)};
  *(ushort4*)(obf + (size_t)m * 1024 + c) = o;
}

__global__ void misc_init(const float* __restrict__ gmbz,
                          const float* __restrict__ gpbz,
                          float* __restrict__ bias_gm,
                          float* __restrict__ bias_gp,
                          float* __restrict__ ent) {
  const int i = blockIdx.x * 256 + threadIdx.x;
  if (i < 2048) {
    bias_gm[i] = (i < 1024) ? gmbz[i] : 0.f;
    bias_gp[i] = (i < 1024) ? gpbz[i] : 0.f;
  }
  if (i < 16) ent[i] = 0.f;
}

// ---------------------------------------------------------------------------
extern "C" void kernel_launch(void* const* d_in, const int* in_sizes, int n_in,
                              void* d_out, int out_size, void* d_ws,
                              size_t ws_size, hipStream_t stream) {
  (void)in_sizes; (void)n_in; (void)out_size; (void)ws_size;
  const float* w      = (const float*)d_in[0];
  const float* r      = (const float*)d_in[2];
  const float* rwb    = (const float*)d_in[3];
  const float* rrb    = (const float*)d_in[4];
  const float* mems   = (const float*)d_in[1];
  const float* ln_a_w = (const float*)d_in[6];
  const float* ln_a_b = (const float*)d_in[7];
  const float* W_qkv  = (const float*)d_in[8];
  const float* W_r    = (const float*)d_in[9];
  const float* W_o    = (const float*)d_in[10];
  const float* ln2_w  = (const float*)d_in[11];
  const float* ln2_b  = (const float*)d_in[12];
  const float* ff_W1  = (const float*)d_in[13];
  const float* ff_b1  = (const float*)d_in[14];
  const float* ff_W2  = (const float*)d_in[15];
  const float* ff_b2  = (const float*)d_in[16];
  const float* gm_Wr  = (const float*)d_in[17];
  const float* gm_Ur  = (const float*)d_in[18];
  const float* gm_Uz  = (const float*)d_in[19];
  const float* gm_Wg  = (const float*)d_in[20];
  const float* gm_Ug  = (const float*)d_in[21];
  const float* gm_Wz  = (const float*)d_in[22];
  const float* gm_bz  = (const float*)d_in[23];
  const float* gp_Wr  = (const float*)d_in[24];
  const float* gp_Ur  = (const float*)d_in[25];
  const float* gp_Uz  = (const float*)d_in[26];
  const float* gp_Wg  = (const float*)d_in[27];
  const float* gp_Ug  = (const float*)d_in[28];
  const float* gp_Wz  = (const float*)d_in[29];
  const float* gp_bz  = (const float*)d_in[30];

  float* out = (float*)d_out;
  float* ent = out + (size_t)NROWS * DM;

  // ---- workspace carve (bytes) ----
  char* base = (char*)d_ws;
  size_t o = 0;
  unsigned short* wt_qkv   = (unsigned short*)(base + o); o += (size_t)3072 * 1024 * 2;
  unsigned short* wt_r     = (unsigned short*)(base + o); o += (size_t)1024 * 1024 * 2;
  unsigned short* wt_o     = (unsigned short*)(base + o); o += (size_t)1024 * 1024 * 2;
  unsigned short* wt_gm_zr = (unsigned short*)(base + o); o += (size_t)2048 * 2048 * 2;
  unsigned short* wt_gm_g  = (unsigned short*)(base + o); o += (size_t)1024 * 2048 * 2;
  unsigned short* wt_gp_zr = (unsigned short*)(base + o); o += (size_t)2048 * 2048 * 2;
  unsigned short* wt_gp_g  = (unsigned short*)(base + o); o += (size_t)1024 * 2048 * 2;
  unsigned short* wt_ff1   = (unsigned short*)(base + o); o += (size_t)4096 * 1024 * 2;
  unsigned short* wt_ff2   = (unsigned short*)(base + o); o += (size_t)1024 * 4096 * 2;
  float* bias_gm = (float*)(base + o); o += 2048 * 4;
  float* bias_gp = (float*)(base + o); o += 2048 * 4;
  unsigned short* Q_g  = (unsigned short*)(base + o); o += (size_t)BSZ * NH * QLEN * DH * 2;
  unsigned short* K_g  = (unsigned short*)(base + o); o += (size_t)BSZ * NH * KLEN * DH * 2;
  unsigned short* V_gT = (unsigned short*)(base + o); o += (size_t)BSZ * NH * DH * KLEN * 2;
  unsigned short* rk_g = (unsigned short*)(base + o); o += (size_t)NH * KLEN * DH * 2;
  unsigned short* lncat_bf = (unsigned short*)(base + o); o += (size_t)HR * DM * 2;
  unsigned short* r_bf = (unsigned short*)(base + o); o += (size_t)KLEN * DM * 2;
  unsigned short* attnb_bf = (unsigned short*)(base + o); o += (size_t)NROWS * DM * 2;
  unsigned short* Ayx = (unsigned short*)(base + o); o += (size_t)NROWS * 2048 * 2;
  float* zr   = (float*)(base + o); o += (size_t)NROWS * 2048 * 4;
  float* hbuf = (float*)(base + o); o += (size_t)NROWS * DM * 4;
  float* o1f  = (float*)(base + o); o += (size_t)NROWS * DM * 4;
  unsigned short* lnb_bf = (unsigned short*)(base + o); o += (size_t)NROWS * DM * 2;
  unsigned short* ffh_bf = (unsigned short*)(base + o); o += (size_t)NROWS * DI * 2;

  // ---- phase 0: batched weight transposes + misc init ----
  TDescs ds;
  int nt = 0, tb = 0;
  auto add = [&](const float* s, unsigned short* d, int N, int K, int stride,
                 int colOff) {
    ds.d[nt] = {s, d, N, stride, colOff, N / 64, tb};
    tb += (N / 64) * (K / 64);
    nt++;
  };
  add(W_qkv, wt_qkv, 3072, 1024, 1024, 0);
  add(W_r, wt_r, 1024, 1024, 1024, 0);
  add(W_o, wt_o, 1024, 1024, 1024, 0);
  add(gm_Wz, wt_gm_zr, 1024, 1024, 2048, 0);
  add(gm_Uz, wt_gm_zr, 1024, 1024, 2048, 1024);
  add(gm_Wr, wt_gm_zr + (size_t)1024 * 2048, 1024, 1024, 2048, 0);
  add(gm_Ur, wt_gm_zr + (size_t)1024 * 2048, 1024, 1024, 2048, 1024);
  add(gm_Wg, wt_gm_g, 1024, 1024, 2048, 0);
  add(gm_Ug, wt_gm_g, 1024, 1024, 2048, 1024);
  add(gp_Wz, wt_gp_zr, 1024, 1024, 2048, 0);
  add(gp_Uz, wt_gp_zr, 1024, 1024, 2048, 1024);
  add(gp_Wr, wt_gp_zr + (size_t)1024 * 2048, 1024, 1024, 2048, 0);
  add(gp_Ur, wt_gp_zr + (size_t)1024 * 2048, 1024, 1024, 2048, 1024);
  add(gp_Wg, wt_gp_g, 1024, 1024, 2048, 0);
  add(gp_Ug, wt_gp_g, 1024, 1024, 2048, 1024);
  add(ff_W1, wt_ff1, 4096, 1024, 1024, 0);
  add(ff_W2, wt_ff2, 1024, 4096, 4096, 0);
  ds.n = nt;
  castT_batch<<<tb, 256, 0, stream>>>(ds);
  misc_init<<<8, 256, 0, stream>>>(gm_bz, gp_bz, bias_gm, bias_gp, ent);

  // ---- phase 1: LN + QKV / r projections (per-head dense outputs) ----
  ln_kernel<true><<<HR, 256, 0, stream>>>(mems, w, ln_a_w, ln_a_b, lncat_bf);
  mgemm<128, ACT_NONE, false, MODE_QKV, true><<<dim3(24, 32), 256, 0, stream>>>(
      lncat_bf, wt_qkv, nullptr, nullptr, nullptr, Q_g, K_g, V_gT,
      HR, HC, 1024, 0);
  castRows<<<1024, 256, 0, stream>>>(r, r_bf, 1024);
  mgemm<64, ACT_NONE, false, MODE_RK, true><<<dim3(8, 16), 256, 0, stream>>>(
      r_bf, wt_r, nullptr, nullptr, nullptr, rk_g, nullptr, nullptr,
      KLEN, 1024, 1024, 0);

  // ---- phase 2: fused attention ----
  fused_attn<<<dim3(8, NH, BSZ), 256, 0, stream>>>(Q_g, K_g, V_gT, rk_g,
                                                   rwb, rrb, attnb_bf, ent);

  // ---- phase 3: W_o (+copy x=w) + gm GRU gate ----
  mgemm<64, ACT_RELU, false, MODE_NORM, true><<<dim3(8, 32), 256, 0, stream>>>(
      attnb_bf, wt_o, Ayx, nullptr, w, nullptr, nullptr, nullptr,
      NROWS, 1024, 1024, 2048);
  mgemm<128, ACT_SIG, true, MODE_NORM, false><<<dim3(16, 16), 256, 0, stream>>>(
      Ayx, wt_gm_zr, zr, bias_gm, nullptr, nullptr, nullptr, nullptr,
      NROWS, 2048, 2048, 2048);
  ew_rx<<<2048, 256, 0, stream>>>(zr, w, Ayx);
  mgemm<64, ACT_TANH, false, MODE_NORM, false><<<dim3(8, 32), 256, 0, stream>>>(
      Ayx, wt_gm_g, hbuf, nullptr, nullptr, nullptr, nullptr, nullptr,
      NROWS, 1024, 2048, 1024);
  ew_out_ln<<<NROWS, 256, 0, stream>>>(zr, w, hbuf, ln2_w, ln2_b, o1f, lnb_bf);

  // ---- phase 4: FF ----
  mgemm<128, ACT_RELU, true, MODE_NORM, true><<<dim3(32, 16), 256, 0, stream>>>(
      lnb_bf, wt_ff1, ffh_bf, ff_b1, nullptr, nullptr, nullptr, nullptr,
      NROWS, DI, 1024, DI);
  mgemm<64, ACT_RELU, true, MODE_NORM, true><<<dim3(8, 32), 256, 0, stream>>>(
      ffh_bf, wt_ff2, Ayx, ff_b2, o1f, nullptr, nullptr, nullptr,
      NROWS, 1024, DI, 2048);

  // ---- phase 5: gp GRU gate ----
  mgemm<128, ACT_SIG, true, MODE_NORM, false><<<dim3(16, 16), 256, 0, stream>>>(
      Ayx, wt_gp_zr, zr, bias_gp, nullptr, nullptr, nullptr, nullptr,
      NROWS, 2048, 2048, 2048);
  ew_rx<<<2048, 256, 0, stream>>>(zr, o1f, Ayx);
  mgemm<64, ACT_TANH, false, MODE_NORM, false><<<dim3(8, 32), 256, 0, stream>>>(
      Ayx, wt_gp_g, hbuf, nullptr, nullptr, nullptr, nullptr, nullptr,
      NROWS, 1024, 2048, 1024);
  ew_out<<<2048, 256, 0, stream>>>(zr, o1f, hbuf, out);
}